// Round 16
// baseline (146.829 us; speedup 1.0000x reference)
//
#include <hip/hip_runtime.h>
#include <hip/hip_bf16.h>
#include <stdint.h>

#define NB 16
#define NS 1024
#define ND 512
#define NO 512
#define NROW (NB*NS)   // 16384
#define SIM_BAND 1.5e-3f
#define LIST_CAP 524288

typedef float f32x4 __attribute__((ext_vector_type(4)));
typedef _Float16 f16x8 __attribute__((ext_vector_type(8)));

#define GLOAD_LDS16(g, l) __builtin_amdgcn_global_load_lds( \
    (const __attribute__((address_space(1))) void*)(g), \
    (__attribute__((address_space(3))) void*)(l), 16, 0, 0)

// ---------------- K1: merged W-prep: blocks 0..31 = Wf frag tiles (f16), 32..33 = watt ----------------
__global__ __launch_bounds__(256) void k_prep_w2(const float* __restrict__ W,
                                                 const float* __restrict__ att_src,
                                                 const float* __restrict__ att_dst,
                                                 _Float16* __restrict__ Wf,
                                                 float* __restrict__ watt_s,
                                                 float* __restrict__ watt_d) {
  __shared__ float as_[512], ad_[512];
  int blk = blockIdx.x, tid = threadIdx.x;
  if (blk < 32) {
    int mt = blk>>3, k0c = blk&7;
    size_t base = ((size_t)(mt*8 + k0c))*8192;
    #pragma unroll
    for (int pp = 0; pp < 4; ++pp) {
      int id = pp*256 + tid;
      int kb = id>>9, m = (id>>6)&7, g = (id>>4)&3, r = id&15;
      int o = mt*128 + m*16 + r;
      int d0 = k0c*64 + kb*32 + g*8;
      union { _Float16 h[8]; uint4 u; } pk;
      #pragma unroll
      for (int j = 0; j < 8; ++j) pk.h[j] = (_Float16)W[(size_t)(d0+j)*NO + o];
      *(uint4*)&Wf[base + id*8] = pk.u;
    }
  } else {
    as_[tid] = att_src[tid]; as_[tid+256] = att_src[tid+256];
    ad_[tid] = att_dst[tid]; ad_[tid+256] = att_dst[tid+256];
    __syncthreads();
    int d = (blk-32)*256 + tid;
    const float* wr = W + (size_t)d*NO;
    float s = 0.f, dd = 0.f;
    for (int o = 0; o < NO; o += 4) {
      float4 w = *(const float4*)&wr[o];
      s  = fmaf(w.x, as_[o], fmaf(w.y, as_[o+1], fmaf(w.z, as_[o+2], fmaf(w.w, as_[o+3], s))));
      dd = fmaf(w.x, ad_[o], fmaf(w.y, ad_[o+1], fmaf(w.z, ad_[o+2], fmaf(w.w, ad_[o+3], dd))));
    }
    watt_s[d] = s;
    watt_d[d] = dd;
  }
}

// ---------------- K2: rnorm + a_src/a_dst (via watt) + yf = f16(x*rn) fragment-order ----------------
__global__ __launch_bounds__(256) void k_prep_y(const float* __restrict__ x,
                                                _Float16* __restrict__ yf,
                                                float* __restrict__ rnorm,
                                                float* __restrict__ a_src,
                                                float* __restrict__ a_dst,
                                                const float* __restrict__ watt_s,
                                                const float* __restrict__ watt_d,
                                                int* __restrict__ counter) {
  __shared__ float ws_[512], wd_[512];
  int tid = threadIdx.x, blk = blockIdx.x;
  if (blk == 0 && tid == 0) *counter = 0;
  ws_[tid] = watt_s[tid]; ws_[tid+256] = watt_s[tid+256];
  wd_[tid] = watt_d[tid]; wd_[tid+256] = watt_d[tid+256];
  __syncthreads();
  int r = tid>>2, q = tid&3;
  int grow = blk*64 + r;
  const float* xr = x + (size_t)grow*ND + q*128;
  float ssq = 0.f, as = 0.f, ad = 0.f;
  #pragma unroll
  for (int c8 = 0; c8 < 16; ++c8) {
    float4 v0 = *(const float4*)&xr[c8*8];
    float4 v1 = *(const float4*)&xr[c8*8+4];
    float vv[8] = {v0.x,v0.y,v0.z,v0.w,v1.x,v1.y,v1.z,v1.w};
    #pragma unroll
    for (int j = 0; j < 8; ++j) {
      int c = q*128 + c8*8 + j;
      ssq = fmaf(vv[j], vv[j], ssq);
      as  = fmaf(vv[j], ws_[c], as);
      ad  = fmaf(vv[j], wd_[c], ad);
    }
  }
  ssq += __shfl_xor(ssq, 1, 64); ssq += __shfl_xor(ssq, 2, 64);
  as  += __shfl_xor(as, 1, 64);  as  += __shfl_xor(as, 2, 64);
  ad  += __shfl_xor(ad, 1, 64);  ad  += __shfl_xor(ad, 2, 64);
  float rn = 1.0f / fmaxf(sqrtf(ssq), 1e-12f);
  if (q == 0) { rnorm[grow] = rn; a_src[grow] = as; a_dst[grow] = ad; }
  int trow = grow & (NS-1), b = grow >> 10;
  int m = (trow>>4)&7, rr = trow&15;
  size_t tilebase = ((size_t)(b*8 + (trow>>7)))*65536;
  #pragma unroll
  for (int c8 = 0; c8 < 16; ++c8) {
    int col = q*128 + c8*8;
    int k0c = col>>6, cc = col&63, kb = cc>>5, g = (cc>>3)&3;
    int id = kb*512 + m*64 + g*16 + rr;
    size_t off = tilebase + (size_t)k0c*8192 + id*8;
    float4 v0 = *(const float4*)&xr[c8*8];
    float4 v1 = *(const float4*)&xr[c8*8+4];
    float vv[8] = {v0.x,v0.y,v0.z,v0.w,v1.x,v1.y,v1.z,v1.w};
    union { _Float16 h[8]; uint4 u; } pk;
    #pragma unroll
    for (int j = 0; j < 8; ++j) pk.h[j] = (_Float16)(vv[j]*rn);   // RTN f16, rel err <= 2^-12
    *(uint4*)&yf[off] = pk.u;
  }
}

// ---------------- K3: sim = yf . yf' (f16 MFMA hi-only) -> BIT mask (ballot) + borderline list ----
__global__ __launch_bounds__(256) void k_sim_mfma(const _Float16* __restrict__ yf,
                                                  uint16_t* __restrict__ Mbits,
                                                  unsigned int* __restrict__ list,
                                                  int* __restrict__ counter) {
  int bid = blockIdx.x;
  int swz = (bid & 7)*72 + (bid >> 3);      // bijective: 576 = 8*72
  int b = swz / 36, p = swz - b*36;
  int ti = 0;
  while ((ti+1)*(ti+2)/2 <= p) ++ti;
  int tj = p - ti*(ti+1)/2;                 // tj <= ti
  __shared__ _Float16 Ah[8192], Bh2[8192];  // 32 KiB
  int tid = threadIdx.x, wid = tid>>6, lane = tid&63;
  int wm = (wid>>1)*64, wn = (wid&1)*64;
  bool diag = (ti == tj);
  const _Float16* Bh = diag ? Ah : Bh2;
  size_t Abase = ((size_t)(b*8+ti))*65536;
  size_t Bbase = ((size_t)(b*8+tj))*65536;
  f32x4 acc[4][4] = {};
  for (int k0c = 0; k0c < 8; ++k0c) {
    __syncthreads();
    size_t ga = Abase + (size_t)k0c*8192 + wid*2048 + lane*8;
    size_t gb = Bbase + (size_t)k0c*8192 + wid*2048 + lane*8;
    int lb = wid*2048;
    #pragma unroll
    for (int i = 0; i < 4; ++i) GLOAD_LDS16(yf + ga + i*512, &Ah[lb + i*512]);
    if (!diag) {
      #pragma unroll
      for (int i = 0; i < 4; ++i) GLOAD_LDS16(yf + gb + i*512, &Bh2[lb + i*512]);
    }
    __syncthreads();
    #pragma unroll
    for (int kb = 0; kb < 2; ++kb) {
      f16x8 ah[4], bh[4];
      #pragma unroll
      for (int q = 0; q < 4; ++q) {
        ah[q] = *(const f16x8*)&Ah[((kb*8 + (wm>>4) + q)*64 + lane)*8];
        bh[q] = *(const f16x8*)&Bh[((kb*8 + (wn>>4) + q)*64 + lane)*8];
      }
      #pragma unroll
      for (int mi = 0; mi < 4; ++mi)
        #pragma unroll
        for (int ni = 0; ni < 4; ++ni)
          acc[mi][ni] = __builtin_amdgcn_mfma_f32_16x16x32_f16(ah[mi], bh[ni], acc[mi][ni], 0,0,0);
    }
  }
  int hi = lane>>4, colL = lane&15;
  #pragma unroll
  for (int mi = 0; mi < 4; ++mi) {
    #pragma unroll
    for (int r2 = 0; r2 < 4; ++r2) {
      int t_g = ti*128 + wm + mi*16 + hi*4 + r2;
      int git = b*NS + t_g;
      #pragma unroll
      for (int ni = 0; ni < 4; ++ni) {
        int s_g = tj*128 + wn + ni*16 + colL;
        float sim = acc[mi][ni][r2];
        bool bit = (s_g == t_g) || (s_g < t_g && sim > 0.9f);
        if (s_g < t_g && fabsf(sim - 0.9f) <= SIM_BAND) {
          int idx = atomicAdd(counter, 1);
          if (idx < LIST_CAP) list[idx] = ((unsigned)b<<20) | ((unsigned)t_g<<10) | (unsigned)s_g;
        }
        unsigned long long bal = __ballot(bit);
        if (colL == 0) {
          uint16_t slice = (uint16_t)((bal >> (hi*16)) & 0xFFFFull);
          Mbits[(size_t)git*64 + ((tj*128 + wn + ni*16)>>4)] = slice;
        }
      }
    }
  }
}

// ---------------- K4 (fused): blocks 0..511 = gemm_ht; 512..767 = bit recheck ----------------
#define HT2_STAGE(OFF, ks) do { \
    size_t ga_ = Abase + (size_t)(ks)*4096 + wid*1024 + lane*8; \
    size_t gb_ = Bbase + (size_t)(ks)*4096 + wid*1024 + lane*8; \
    int lb_ = wid*1024; \
    GLOAD_LDS16(Wf + ga_,       &sbuf[(OFF) + lb_]); \
    GLOAD_LDS16(Wf + ga_ + 512, &sbuf[(OFF) + lb_ + 512]); \
    GLOAD_LDS16(yf + gb_,       &sbuf[(OFF) + 4096 + lb_]); \
    GLOAD_LDS16(yf + gb_ + 512, &sbuf[(OFF) + 4096 + lb_ + 512]); \
  } while(0)

#define HT2_COMPUTE(OFF) do { \
    f16x8 a_[4], b_[4]; \
    _Pragma("unroll") \
    for (int q_ = 0; q_ < 4; ++q_) { \
      a_[q_] = *(const f16x8*)&sbuf[(OFF) + (((wm>>4) + q_)*64 + lane)*8]; \
      b_[q_] = *(const f16x8*)&sbuf[(OFF) + 4096 + (((wn>>4) + q_)*64 + lane)*8]; \
    } \
    _Pragma("unroll") \
    for (int mi_ = 0; mi_ < 4; ++mi_) \
      _Pragma("unroll") \
      for (int ni_ = 0; ni_ < 4; ++ni_) \
        acc[mi_][ni_] = __builtin_amdgcn_mfma_f32_16x16x32_f16(a_[mi_], b_[ni_], acc[mi_][ni_], 0,0,0); \
  } while(0)

__global__ __launch_bounds__(256) void k_ht_recheck(const _Float16* __restrict__ Wf,
                                                    const _Float16* __restrict__ yf,
                                                    const float* __restrict__ x,
                                                    const float* __restrict__ rnorm,
                                                    _Float16* __restrict__ htf,
                                                    uint32_t* __restrict__ Mw,
                                                    const unsigned int* __restrict__ list,
                                                    const int* __restrict__ counter) {
  __shared__ __align__(16) _Float16 sbuf[16384];   // 32 KiB arena
  int bid0 = blockIdx.x;
  if (bid0 < 512) {
    int swz = (bid0&7)*64 + (bid0>>3);        // bijective: 512 = 8*64
    int mt = swz&3, it = swz>>2;
    int b = it>>3, tblk = it&7;
    int tid = threadIdx.x, wid = tid>>6, lane = tid&63;
    int wm = (wid>>1)*64, wn = (wid&1)*64;
    size_t Abase = ((size_t)mt)*65536;
    size_t Bbase = ((size_t)(b*8+tblk))*65536;
    f32x4 acc[4][4] = {};
    HT2_STAGE(0, 0);
    __syncthreads();
    for (int kp = 0; kp < 8; ++kp) {
      HT2_STAGE(8192, kp*2+1);
      HT2_COMPUTE(0);
      __syncthreads();
      if (kp < 7) HT2_STAGE(0, kp*2+2);
      HT2_COMPUTE(8192);
      __syncthreads();
    }
    {
      int rbase = (lane>>4)*4, colL = lane&15;
      #pragma unroll
      for (int ni = 0; ni < 4; ++ni) {
        int i_local = wn + ni*16 + colL;
        int gn = it*128 + i_local;
        float xn = 1.0f / rnorm[gn];
        int tsel = i_local>>6, ic = i_local&63;
        int kb = ic>>5, g = (ic>>3)&3, j = ic&7;
        int base = tsel*8192 + (kb*512 + g*16)*8 + j;
        #pragma unroll
        for (int mi = 0; mi < 4; ++mi)
          #pragma unroll
          for (int r2 = 0; r2 < 4; ++r2) {
            int o_local = wm + mi*16 + rbase + r2;
            int m = o_local>>4, r = o_local&15;
            sbuf[base + (m*64 + r)*8] = (_Float16)(acc[mi][ni][r2] * xn);
          }
      }
    }
    __syncthreads();
    {
      size_t gbase = ((size_t)((mt*NB + b)*16 + tblk*2))*8192;
      const uint4* src = (const uint4*)sbuf;
      uint4* dst = (uint4*)(htf + gbase);
      #pragma unroll
      for (int k = 0; k < 8; ++k) dst[tid + k*256] = src[tid + k*256];
    }
  } else {
    int n = *counter;
    if (n > LIST_CAP) n = LIST_CAP;
    int gid = (bid0 - 512)*256 + threadIdx.x;
    for (int i = gid; i < n; i += 256*256) {
      unsigned v = list[i];
      int b = v>>20, t = (v>>10)&1023, s = v&1023;
      const float* xt = x + ((size_t)(b*NS + t))*ND;
      const float* xs = x + ((size_t)(b*NS + s))*ND;
      float4 a4 = {0.f,0.f,0.f,0.f};
      for (int k = 0; k < ND; k += 4) {
        float4 av = *(const float4*)&xt[k];
        float4 bv = *(const float4*)&xs[k];
        a4.x = fmaf(av.x,bv.x,a4.x); a4.y = fmaf(av.y,bv.y,a4.y);
        a4.z = fmaf(av.z,bv.z,a4.z); a4.w = fmaf(av.w,bv.w,a4.w);
      }
      float dot = (a4.x+a4.y)+(a4.z+a4.w);
      float sim = dot * rnorm[b*NS+t] * rnorm[b*NS+s];
      int git = b*NS + t;
      uint32_t bmask = 1u << (s&31);
      if (sim > 0.9f) atomicOr (&Mw[(size_t)git*32 + (s>>5)], bmask);
      else            atomicAnd(&Mw[(size_t)git*32 + (s>>5)], ~bmask);
    }
  }
}

// ---------------- K5: row stats (max, 1/sum) from bit mask -- softmax reduction only ----------------
__global__ __launch_bounds__(256) void k_stats(const uint32_t* __restrict__ Mw,
                                               const float* __restrict__ a_src,
                                               const float* __restrict__ a_dst,
                                               float* __restrict__ mrow,
                                               float* __restrict__ linv) {
  int wid = threadIdx.x>>6, lane = threadIdx.x&63;
  int rowid = blockIdx.x*4 + wid;           // grid 4096
  int t = rowid & (NS-1), b = rowid >> 10;
  int n = t + 1;
  const float* as = a_src + b*NS;
  float adv = a_dst[rowid];
  uint32_t w = Mw[(size_t)rowid*32 + (lane>>1)];
  uint32_t bits16 = (lane&1) ? (w>>16) : (w & 0xFFFFu);
  int s0 = lane*16;
  float4 a0 = *(const float4*)&as[s0];
  float4 a1 = *(const float4*)&as[s0+4];
  float4 a2 = *(const float4*)&as[s0+8];
  float4 a3 = *(const float4*)&as[s0+12];
  float va[16] = {a0.x,a0.y,a0.z,a0.w, a1.x,a1.y,a1.z,a1.w,
                  a2.x,a2.y,a2.z,a2.w, a3.x,a3.y,a3.z,a3.w};
  float pr[16];
  float lm = -INFINITY;
  #pragma unroll
  for (int k = 0; k < 16; ++k) {
    int s = s0 + k;
    bool on = (s < n) && ((bits16>>k)&1);
    float vv = adv + va[k];
    float v = (vv > 0.f) ? vv : 0.2f*vv;
    pr[k] = on ? v : -INFINITY;
    lm = fmaxf(lm, pr[k]);
  }
  #pragma unroll
  for (int off = 32; off > 0; off >>= 1) lm = fmaxf(lm, __shfl_xor(lm, off, 64));
  float ls = 0.f;
  #pragma unroll
  for (int k = 0; k < 16; ++k) ls += __expf(pr[k] - lm);
  #pragma unroll
  for (int off = 32; off > 0; off >>= 1) ls += __shfl_xor(ls, off, 64);
  if (lane == 0) { mrow[rowid] = lm; linv[rowid] = 1.0f / ls; }
}

// ---------------- K6: out = relu(P @ h + bias); P built ON THE FLY from bits+stats ----------------
#define PVF_BUILD(AB, ks) do { \
    int ks_ = (ks); \
    _Pragma("unroll") \
    for (int ii_ = 0; ii_ < 2; ++ii_) { \
      int id_ = ii_*256 + tid; \
      int m_ = id_>>6, g_ = (id_>>4)&3, r_ = id_&15; \
      int tl_ = m_*16 + r_; \
      int s0_ = ks_*32 + g_*8; \
      float mv_ = sm[tl_], iv_ = si[tl_], av_ = sa[tl_]; \
      unsigned w_ = Mrow0[(size_t)tl_*64 + (s0_>>4)]; \
      int sh_ = s0_ & 15; \
      union { _Float16 h[8]; uint4 u; } pk_; \
      _Pragma("unroll") \
      for (int j_ = 0; j_ < 8; ++j_) { \
        float vv_ = av_ + sas[s0_ + j_]; \
        float v_ = (vv_ > 0.f) ? vv_ : 0.2f*vv_; \
        float p_ = ((w_ >> (sh_ + j_)) & 1u) ? __expf(v_ - mv_)*iv_ : 0.f; \
        pk_.h[j_] = (_Float16)p_; \
      } \
      *(uint4*)&AB[id_*8] = pk_.u; \
    } \
  } while(0)

#define PVF_BSTAGE(BT, ks) do { \
    size_t gb_ = Bbase + (size_t)(ks)*4096 + wid*1024 + lane*8; \
    int lb_ = wid*1024; \
    GLOAD_LDS16(htf + gb_,       &BT[lb_]); \
    GLOAD_LDS16(htf + gb_ + 512, &BT[lb_ + 512]); \
  } while(0)

#define F16_COMPUTE2(AW, BW) do { \
    f16x8 a_[4], b_[4]; \
    _Pragma("unroll") \
    for (int q_ = 0; q_ < 4; ++q_) { \
      a_[q_] = *(const f16x8*)&(AW)[(((wm>>4) + q_)*64 + lane)*8]; \
      b_[q_] = *(const f16x8*)&(BW)[(((wn>>4) + q_)*64 + lane)*8]; \
    } \
    _Pragma("unroll") \
    for (int mi_ = 0; mi_ < 4; ++mi_) \
      _Pragma("unroll") \
      for (int ni_ = 0; ni_ < 4; ++ni_) \
        acc[mi_][ni_] = __builtin_amdgcn_mfma_f32_16x16x32_f16(a_[mi_], b_[ni_], acc[mi_][ni_], 0,0,0); \
  } while(0)

__global__ __launch_bounds__(256) void k_pv(const _Float16* __restrict__ htf,
                                            const uint16_t* __restrict__ Mbits,
                                            const float* __restrict__ a_src,
                                            const float* __restrict__ a_dst,
                                            const float* __restrict__ mrow,
                                            const float* __restrict__ linv,
                                            const float* __restrict__ bias,
                                            float* __restrict__ out) {
  int bid = blockIdx.x;
  int swz = (bid&7)*64 + (bid>>3);          // bijective: 512 = 8*64
  int b = swz>>5, rem = swz&31, mt = rem>>2, nt = rem&3;
  __shared__ __align__(16) _Float16 Ab0[4096], Ab1[4096], Bt0[4096], Bt1[4096];  // 32 KiB
  __shared__ float sas[1024];
  __shared__ float sm[128], si[128], sa[128];
  int tid = threadIdx.x, wid = tid>>6, lane = tid&63;
  int wm = (wid>>1)*64, wn = (wid&1)*64;
  int nks = 4*(mt+1);                       // even; causal extent
  int kext = nks*32;
  for (int u = tid; u < kext; u += 256) sas[u] = a_src[b*NS + u];
  if (tid < 128) {
    int rowid = b*NS + mt*128 + tid;
    sm[tid] = mrow[rowid];
    si[tid] = linv[rowid];
    sa[tid] = a_dst[rowid];
  }
  size_t Bbase = ((size_t)((nt*NB + b)*16))*8192;
  const uint16_t* Mrow0 = Mbits + (size_t)(b*NS + mt*128)*64;
  f32x4 acc[4][4] = {};
  __syncthreads();                          // stats/a_src staged
  PVF_BUILD(Ab0, 0);
  PVF_BSTAGE(Bt0, 0);
  __syncthreads();
  for (int kp = 0; kp < nks/2; ++kp) {
    PVF_BUILD(Ab1, kp*2+1);
    PVF_BSTAGE(Bt1, kp*2+1);
    F16_COMPUTE2(Ab0, Bt0);
    __syncthreads();
    if (kp < nks/2 - 1) { PVF_BUILD(Ab0, kp*2+2); PVF_BSTAGE(Bt0, kp*2+2); }
    F16_COMPUTE2(Ab1, Bt1);
    __syncthreads();
  }
  int m0 = mt*128, n0 = nt*128;
  int rbase = (lane>>4)*4, col = lane&15;
  #pragma unroll
  for (int mi = 0; mi < 4; ++mi)
    #pragma unroll
    for (int ni = 0; ni < 4; ++ni) {
      int gm = m0 + wm + mi*16 + rbase;
      int gn = n0 + wn + ni*16 + col;
      float bv = bias[gn];
      #pragma unroll
      for (int r2 = 0; r2 < 4; ++r2)
        out[((size_t)b*NS + gm + r2)*NO + gn] = fmaxf(acc[mi][ni][r2] + bv, 0.0f);
    }
}

extern "C" void kernel_launch(void* const* d_in, const int* in_sizes, int n_in,
                              void* d_out, int out_size, void* d_ws, size_t ws_size,
                              hipStream_t stream) {
  (void)in_sizes; (void)n_in; (void)out_size; (void)ws_size;
  const float* x       = (const float*)d_in[0];
  const float* W       = (const float*)d_in[1];
  const float* att_src = (const float*)d_in[2];
  const float* att_dst = (const float*)d_in[3];
  const float* bias    = (const float*)d_in[4];
  float* out = (float*)d_out;

  char* ws = (char*)d_ws;
  // ws_size = 256 MiB; clean non-aliased layout (~38.6 MB):
  _Float16*     yf    = (_Float16*)    (ws + 0);           // 16 MB [prep_y..ht]
  _Float16*     htf   = (_Float16*)    (ws + 16777216);    // 16 MB [ht..pv]
  uint16_t*     Mbits = (uint16_t*)    (ws + 33554432);    //  2 MB [sim..pv]
  _Float16*     Wf    = (_Float16*)    (ws + 35651584);    // 512 KB [prep_w2..ht]
  float*        watt_s= (float*)       (ws + 36175872);    //  2 KB
  float*        watt_d= (float*)       (ws + 36177920);    //  2 KB
  float*        rnorm = (float*)       (ws + 36179968);    // 64 KB
  float*        a_src = (float*)       (ws + 36245504);    // 64 KB
  float*        a_dst = (float*)       (ws + 36311040);    // 64 KB
  unsigned int* list  = (unsigned int*)(ws + 36376576);    //  2 MB [sim..recheck]
  int*          cnt   = (int*)         (ws + 38473728);    // 64 B
  float*        mrow  = (float*)       (ws + 38473792);    // 64 KB [stats..pv]
  float*        linv  = (float*)       (ws + 38539328);    // 64 KB [stats..pv]

  k_prep_w2   <<<dim3(34),   dim3(256), 0, stream>>>(W, att_src, att_dst, Wf, watt_s, watt_d);
  k_prep_y    <<<dim3(256),  dim3(256), 0, stream>>>(x, yf, rnorm, a_src, a_dst, watt_s, watt_d, cnt);
  k_sim_mfma  <<<dim3(576),  dim3(256), 0, stream>>>(yf, Mbits, list, cnt);
  k_ht_recheck<<<dim3(768),  dim3(256), 0, stream>>>(Wf, yf, x, rnorm, htf, (uint32_t*)Mbits, list, cnt);
  k_stats     <<<dim3(4096), dim3(256), 0, stream>>>((const uint32_t*)Mbits, a_src, a_dst, mrow, linv);
  k_pv        <<<dim3(512),  dim3(256), 0, stream>>>(htf, Mbits, a_src, a_dst, mrow, linv, bias, out);
}

// Round 17
// 131.093 us; speedup vs baseline: 1.1200x; 1.1200x over previous
//
#include <hip/hip_runtime.h>
#include <hip/hip_bf16.h>
#include <stdint.h>

#define NB 16
#define NS 1024
#define ND 512
#define NO 512
#define NROW (NB*NS)   // 16384
#define SIM_BAND 1.5e-3f
#define LIST_CAP 524288

typedef float f32x4 __attribute__((ext_vector_type(4)));
typedef _Float16 f16x8 __attribute__((ext_vector_type(8)));

// ---------------- K1: merged W-prep: blocks 0..31 = Wf frag tiles (f16), 32..33 = watt ----------------
__global__ __launch_bounds__(256) void k_prep_w2(const float* __restrict__ W,
                                                 const float* __restrict__ att_src,
                                                 const float* __restrict__ att_dst,
                                                 _Float16* __restrict__ Wf,
                                                 float* __restrict__ watt_s,
                                                 float* __restrict__ watt_d) {
  __shared__ float as_[512], ad_[512];
  int blk = blockIdx.x, tid = threadIdx.x;
  if (blk < 32) {
    int mt = blk>>3, k0c = blk&7;
    size_t base = ((size_t)(mt*8 + k0c))*8192;
    #pragma unroll
    for (int pp = 0; pp < 4; ++pp) {
      int id = pp*256 + tid;
      int kb = id>>9, m = (id>>6)&7, g = (id>>4)&3, r = id&15;
      int o = mt*128 + m*16 + r;
      int d0 = k0c*64 + kb*32 + g*8;
      union { _Float16 h[8]; uint4 u; } pk;
      #pragma unroll
      for (int j = 0; j < 8; ++j) pk.h[j] = (_Float16)W[(size_t)(d0+j)*NO + o];
      *(uint4*)&Wf[base + id*8] = pk.u;
    }
  } else {
    as_[tid] = att_src[tid]; as_[tid+256] = att_src[tid+256];
    ad_[tid] = att_dst[tid]; ad_[tid+256] = att_dst[tid+256];
    __syncthreads();
    int d = (blk-32)*256 + tid;
    const float* wr = W + (size_t)d*NO;
    float s = 0.f, dd = 0.f;
    for (int o = 0; o < NO; o += 4) {
      float4 w = *(const float4*)&wr[o];
      s  = fmaf(w.x, as_[o], fmaf(w.y, as_[o+1], fmaf(w.z, as_[o+2], fmaf(w.w, as_[o+3], s))));
      dd = fmaf(w.x, ad_[o], fmaf(w.y, ad_[o+1], fmaf(w.z, ad_[o+2], fmaf(w.w, ad_[o+3], dd))));
    }
    watt_s[d] = s;
    watt_d[d] = dd;
  }
}

// ---------------- K2: rnorm + a_src/a_dst (via watt) + yf = f16(x*rn) fragment-order ----------------
__global__ __launch_bounds__(256) void k_prep_y(const float* __restrict__ x,
                                                _Float16* __restrict__ yf,
                                                float* __restrict__ rnorm,
                                                float* __restrict__ a_src,
                                                float* __restrict__ a_dst,
                                                const float* __restrict__ watt_s,
                                                const float* __restrict__ watt_d,
                                                int* __restrict__ counter) {
  __shared__ float ws_[512], wd_[512];
  int tid = threadIdx.x, blk = blockIdx.x;
  if (blk == 0 && tid == 0) *counter = 0;
  ws_[tid] = watt_s[tid]; ws_[tid+256] = watt_s[tid+256];
  wd_[tid] = watt_d[tid]; wd_[tid+256] = watt_d[tid+256];
  __syncthreads();
  int r = tid>>2, q = tid&3;
  int grow = blk*64 + r;
  const float* xr = x + (size_t)grow*ND + q*128;
  float ssq = 0.f, as = 0.f, ad = 0.f;
  #pragma unroll
  for (int c8 = 0; c8 < 16; ++c8) {
    float4 v0 = *(const float4*)&xr[c8*8];
    float4 v1 = *(const float4*)&xr[c8*8+4];
    float vv[8] = {v0.x,v0.y,v0.z,v0.w,v1.x,v1.y,v1.z,v1.w};
    #pragma unroll
    for (int j = 0; j < 8; ++j) {
      int c = q*128 + c8*8 + j;
      ssq = fmaf(vv[j], vv[j], ssq);
      as  = fmaf(vv[j], ws_[c], as);
      ad  = fmaf(vv[j], wd_[c], ad);
    }
  }
  ssq += __shfl_xor(ssq, 1, 64); ssq += __shfl_xor(ssq, 2, 64);
  as  += __shfl_xor(as, 1, 64);  as  += __shfl_xor(as, 2, 64);
  ad  += __shfl_xor(ad, 1, 64);  ad  += __shfl_xor(ad, 2, 64);
  float rn = 1.0f / fmaxf(sqrtf(ssq), 1e-12f);
  if (q == 0) { rnorm[grow] = rn; a_src[grow] = as; a_dst[grow] = ad; }
  int trow = grow & (NS-1), b = grow >> 10;
  int m = (trow>>4)&7, rr = trow&15;
  size_t tilebase = ((size_t)(b*8 + (trow>>7)))*65536;
  #pragma unroll
  for (int c8 = 0; c8 < 16; ++c8) {
    int col = q*128 + c8*8;
    int k0c = col>>6, cc = col&63, kb = cc>>5, g = (cc>>3)&3;
    int id = kb*512 + m*64 + g*16 + rr;
    size_t off = tilebase + (size_t)k0c*8192 + id*8;
    float4 v0 = *(const float4*)&xr[c8*8];
    float4 v1 = *(const float4*)&xr[c8*8+4];
    float vv[8] = {v0.x,v0.y,v0.z,v0.w,v1.x,v1.y,v1.z,v1.w};
    union { _Float16 h[8]; uint4 u; } pk;
    #pragma unroll
    for (int j = 0; j < 8; ++j) pk.h[j] = (_Float16)(vv[j]*rn);   // RTN f16, rel err <= 2^-12
    *(uint4*)&yf[off] = pk.u;
  }
}

// ---------------- K3: sim = yf . yf' -- ZERO-LDS: fragments streamed straight from global ----------
__global__ __launch_bounds__(256) void k_sim_mfma(const _Float16* __restrict__ yf,
                                                  uint16_t* __restrict__ Mbits,
                                                  unsigned int* __restrict__ list,
                                                  int* __restrict__ counter) {
  int bid = blockIdx.x;
  int swz = (bid & 7)*72 + (bid >> 3);      // bijective: 576 = 8*72
  int b = swz / 36, p = swz - b*36;
  int ti = 0;
  while ((ti+1)*(ti+2)/2 <= p) ++ti;
  int tj = p - ti*(ti+1)/2;                 // tj <= ti
  int tid = threadIdx.x, wid = tid>>6, lane = tid&63;
  int wm = (wid>>1)*64, wn = (wid&1)*64;
  size_t Abase = ((size_t)(b*8+ti))*65536 + (size_t)lane*8;
  size_t Bbase = ((size_t)(b*8+tj))*65536 + (size_t)lane*8;
  int aq = (wm>>4), bq = (wn>>4);
  f32x4 acc[4][4] = {};
  for (int k0c = 0; k0c < 8; ++k0c) {
    #pragma unroll
    for (int kb = 0; kb < 2; ++kb) {
      f16x8 ah[4], bh[4];
      #pragma unroll
      for (int q = 0; q < 4; ++q) {
        ah[q] = *(const f16x8*)&yf[Abase + (size_t)k0c*8192 + (size_t)(kb*8 + aq + q)*512];
        bh[q] = *(const f16x8*)&yf[Bbase + (size_t)k0c*8192 + (size_t)(kb*8 + bq + q)*512];
      }
      #pragma unroll
      for (int mi = 0; mi < 4; ++mi)
        #pragma unroll
        for (int ni = 0; ni < 4; ++ni)
          acc[mi][ni] = __builtin_amdgcn_mfma_f32_16x16x32_f16(ah[mi], bh[ni], acc[mi][ni], 0,0,0);
    }
  }
  int hi = lane>>4, colL = lane&15;
  #pragma unroll
  for (int mi = 0; mi < 4; ++mi) {
    #pragma unroll
    for (int r2 = 0; r2 < 4; ++r2) {
      int t_g = ti*128 + wm + mi*16 + hi*4 + r2;
      int git = b*NS + t_g;
      #pragma unroll
      for (int ni = 0; ni < 4; ++ni) {
        int s_g = tj*128 + wn + ni*16 + colL;
        float sim = acc[mi][ni][r2];
        bool bit = (s_g == t_g) || (s_g < t_g && sim > 0.9f);
        if (s_g < t_g && fabsf(sim - 0.9f) <= SIM_BAND) {
          int idx = atomicAdd(counter, 1);
          if (idx < LIST_CAP) list[idx] = ((unsigned)b<<20) | ((unsigned)t_g<<10) | (unsigned)s_g;
        }
        unsigned long long bal = __ballot(bit);
        if (colL == 0) {
          uint16_t slice = (uint16_t)((bal >> (hi*16)) & 0xFFFFull);
          Mbits[(size_t)git*64 + ((tj*128 + wn + ni*16)>>4)] = slice;
        }
      }
    }
  }
}

// ---------------- K4 (fused): blocks 0..511 = gemm_ht (zero-LDS loop); 512..767 = bit recheck ------
__global__ __launch_bounds__(256) void k_ht_recheck(const _Float16* __restrict__ Wf,
                                                    const _Float16* __restrict__ yf,
                                                    const float* __restrict__ x,
                                                    const float* __restrict__ rnorm,
                                                    _Float16* __restrict__ htf,
                                                    uint32_t* __restrict__ Mw,
                                                    const unsigned int* __restrict__ list,
                                                    const int* __restrict__ counter) {
  __shared__ __align__(16) _Float16 sbuf[16384];   // 32 KiB, used ONLY for coalesced output staging
  int bid0 = blockIdx.x;
  if (bid0 < 512) {
    int swz = (bid0&7)*64 + (bid0>>3);        // bijective: 512 = 8*64
    int mt = swz&3, it = swz>>2;
    int b = it>>3, tblk = it&7;
    int tid = threadIdx.x, wid = tid>>6, lane = tid&63;
    int wm = (wid>>1)*64, wn = (wid&1)*64;
    size_t Abase = ((size_t)mt)*65536 + (size_t)lane*8;
    size_t Bbase = ((size_t)(b*8+tblk))*65536 + (size_t)lane*8;
    int aq = (wm>>4), bq = (wn>>4);
    f32x4 acc[4][4] = {};
    for (int k0c = 0; k0c < 8; ++k0c) {
      #pragma unroll
      for (int kb = 0; kb < 2; ++kb) {
        f16x8 a[4], bb[4];
        #pragma unroll
        for (int q = 0; q < 4; ++q) {
          a [q] = *(const f16x8*)&Wf[Abase + (size_t)k0c*8192 + (size_t)(kb*8 + aq + q)*512];
          bb[q] = *(const f16x8*)&yf[Bbase + (size_t)k0c*8192 + (size_t)(kb*8 + bq + q)*512];
        }
        #pragma unroll
        for (int mi = 0; mi < 4; ++mi)
          #pragma unroll
          for (int ni = 0; ni < 4; ++ni)
            acc[mi][ni] = __builtin_amdgcn_mfma_f32_16x16x32_f16(a[mi], bb[ni], acc[mi][ni], 0,0,0);
      }
    }
    {
      int rbase = (lane>>4)*4, colL = lane&15;
      #pragma unroll
      for (int ni = 0; ni < 4; ++ni) {
        int i_local = wn + ni*16 + colL;
        int gn = it*128 + i_local;
        float xn = 1.0f / rnorm[gn];
        int tsel = i_local>>6, ic = i_local&63;
        int kb = ic>>5, g = (ic>>3)&3, j = ic&7;
        int base = tsel*8192 + (kb*512 + g*16)*8 + j;
        #pragma unroll
        for (int mi = 0; mi < 4; ++mi)
          #pragma unroll
          for (int r2 = 0; r2 < 4; ++r2) {
            int o_local = wm + mi*16 + rbase + r2;
            int m = o_local>>4, r = o_local&15;
            sbuf[base + (m*64 + r)*8] = (_Float16)(acc[mi][ni][r2] * xn);
          }
      }
    }
    __syncthreads();
    {
      size_t gbase = ((size_t)((mt*NB + b)*16 + tblk*2))*8192;
      const uint4* src = (const uint4*)sbuf;
      uint4* dst = (uint4*)(htf + gbase);
      #pragma unroll
      for (int k = 0; k < 8; ++k) dst[tid + k*256] = src[tid + k*256];
    }
  } else {
    int n = *counter;
    if (n > LIST_CAP) n = LIST_CAP;
    int gid = (bid0 - 512)*256 + threadIdx.x;
    for (int i = gid; i < n; i += 256*256) {
      unsigned v = list[i];
      int b = v>>20, t = (v>>10)&1023, s = v&1023;
      const float* xt = x + ((size_t)(b*NS + t))*ND;
      const float* xs = x + ((size_t)(b*NS + s))*ND;
      float4 a4 = {0.f,0.f,0.f,0.f};
      for (int k = 0; k < ND; k += 4) {
        float4 av = *(const float4*)&xt[k];
        float4 bv = *(const float4*)&xs[k];
        a4.x = fmaf(av.x,bv.x,a4.x); a4.y = fmaf(av.y,bv.y,a4.y);
        a4.z = fmaf(av.z,bv.z,a4.z); a4.w = fmaf(av.w,bv.w,a4.w);
      }
      float dot = (a4.x+a4.y)+(a4.z+a4.w);
      float sim = dot * rnorm[b*NS+t] * rnorm[b*NS+s];
      int git = b*NS + t;
      uint32_t bmask = 1u << (s&31);
      if (sim > 0.9f) atomicOr (&Mw[(size_t)git*32 + (s>>5)], bmask);
      else            atomicAnd(&Mw[(size_t)git*32 + (s>>5)], ~bmask);
    }
  }
}

// ---------------- K5: masked softmax (bit mask) -> Pf (f16 frag-order), LDS-staged writes ----------
__global__ __launch_bounds__(256) void k_softmax(const uint32_t* __restrict__ Mw,
                                                 const float* __restrict__ a_src,
                                                 const float* __restrict__ a_dst,
                                                 _Float16* __restrict__ Pf) {
  __shared__ __align__(16) _Float16 pbuf[4][1032];
  int wid = threadIdx.x>>6, lane = threadIdx.x&63;
  int rowid = blockIdx.x*4 + wid;           // grid 4096; block rows share pane & m
  int t = rowid & (NS-1), b = rowid >> 10;
  int n = t + 1;
  const float* as = a_src + b*NS;
  float adv = a_dst[rowid];
  uint32_t w = Mw[(size_t)rowid*32 + (lane>>1)];
  uint32_t bits16 = (lane&1) ? (w>>16) : (w & 0xFFFFu);
  int s0 = lane*16;
  float4 a0 = *(const float4*)&as[s0];
  float4 a1 = *(const float4*)&as[s0+4];
  float4 a2 = *(const float4*)&as[s0+8];
  float4 a3 = *(const float4*)&as[s0+12];
  float va[16] = {a0.x,a0.y,a0.z,a0.w, a1.x,a1.y,a1.z,a1.w,
                  a2.x,a2.y,a2.z,a2.w, a3.x,a3.y,a3.z,a3.w};
  float pr[16];
  float lm = -INFINITY;
  #pragma unroll
  for (int k = 0; k < 16; ++k) {
    int s = s0 + k;
    bool on = (s < n) && ((bits16>>k)&1);
    float vv = adv + va[k];
    float v = (vv > 0.f) ? vv : 0.2f*vv;
    pr[k] = on ? v : -INFINITY;
    lm = fmaxf(lm, pr[k]);
  }
  #pragma unroll
  for (int off = 32; off > 0; off >>= 1) lm = fmaxf(lm, __shfl_xor(lm, off, 64));
  float ls = 0.f;
  #pragma unroll
  for (int k = 0; k < 16; ++k) { pr[k] = __expf(pr[k] - lm); ls += pr[k]; }
  #pragma unroll
  for (int off = 32; off > 0; off >>= 1) ls += __shfl_xor(ls, off, 64);
  float inv = 1.0f / ls;
  union { _Float16 hh[8]; uint4 u; } pk0, pk1;
  #pragma unroll
  for (int j = 0; j < 8; ++j) pk0.hh[j] = (_Float16)(pr[j]*inv);
  #pragma unroll
  for (int j = 0; j < 8; ++j) pk1.hh[j] = (_Float16)(pr[8+j]*inv);
  *(uint4*)&pbuf[wid][s0]   = pk0.u;
  *(uint4*)&pbuf[wid][s0+8] = pk1.u;
  __syncthreads();
  int t0 = (blockIdx.x*4) & (NS-1);
  int b0 = (blockIdx.x*4) >> 10;
  int end = ((t0 >> 7) + 1) << 7;
  int m = (t0>>4)&7, r0 = t0&15;
  size_t tbase = ((size_t)(b0*8 + (t0>>7)))*131072;   // pane = 16 tiles x 8192
  int nslots = (end>>3)*4;
  for (int u = threadIdx.x; u < nslots; u += 256) {
    int rr = u&3, c8 = u>>2;
    int icol = c8*8;
    int k0c = icol>>6, kb = (icol>>5)&1, g = (icol>>3)&3;
    uint4 v = *(const uint4*)&pbuf[rr][icol];
    *(uint4*)&Pf[tbase + (size_t)k0c*8192 + (size_t)(kb*512 + m*64 + g*16 + r0 + rr)*8] = v;
  }
}

// ---------------- K6: out = relu(P @ h + bias) -- ZERO-LDS fragment streaming, causal ----------------
__global__ __launch_bounds__(256) void k_pv(const _Float16* __restrict__ Pf,
                                            const _Float16* __restrict__ htf,
                                            const float* __restrict__ bias,
                                            float* __restrict__ out) {
  int bid = blockIdx.x;
  int swz = (bid&7)*64 + (bid>>3);          // bijective: 512 = 8*64
  int b = swz>>5, rem = swz&31, mt = rem>>2, nt = rem&3;
  int tid = threadIdx.x, wid = tid>>6, lane = tid&63;
  int wm = (wid>>1)*64, wn = (wid&1)*64;
  size_t Abase = ((size_t)((b*8 + mt)*16))*8192 + (size_t)lane*8;
  size_t Bbase = ((size_t)((nt*NB + b)*16))*8192 + (size_t)lane*8;
  int aq = (wm>>4), bq = (wn>>4);
  f32x4 acc[4][4] = {};
  int nk0 = 2*(mt+1);                       // causal: k0c tiles
  for (int k0c = 0; k0c < nk0; ++k0c) {
    #pragma unroll
    for (int kb = 0; kb < 2; ++kb) {
      f16x8 a[4], bb[4];
      #pragma unroll
      for (int q = 0; q < 4; ++q) {
        a [q] = *(const f16x8*)&Pf [Abase + (size_t)k0c*8192 + (size_t)(kb*8 + aq + q)*512];
        bb[q] = *(const f16x8*)&htf[Bbase + (size_t)k0c*8192 + (size_t)(kb*8 + bq + q)*512];
      }
      #pragma unroll
      for (int mi = 0; mi < 4; ++mi)
        #pragma unroll
        for (int ni = 0; ni < 4; ++ni)
          acc[mi][ni] = __builtin_amdgcn_mfma_f32_16x16x32_f16(a[mi], bb[ni], acc[mi][ni], 0,0,0);
    }
  }
  int m0 = mt*128, n0 = nt*128;
  int rbase = (lane>>4)*4, col = lane&15;
  #pragma unroll
  for (int mi = 0; mi < 4; ++mi)
    #pragma unroll
    for (int ni = 0; ni < 4; ++ni) {
      int gm = m0 + wm + mi*16 + rbase;
      int gn = n0 + wn + ni*16 + col;
      float bv = bias[gn];
      #pragma unroll
      for (int r2 = 0; r2 < 4; ++r2)
        out[((size_t)b*NS + gm + r2)*NO + gn] = fmaxf(acc[mi][ni][r2] + bv, 0.0f);
    }
}

extern "C" void kernel_launch(void* const* d_in, const int* in_sizes, int n_in,
                              void* d_out, int out_size, void* d_ws, size_t ws_size,
                              hipStream_t stream) {
  (void)in_sizes; (void)n_in; (void)out_size; (void)ws_size;
  const float* x       = (const float*)d_in[0];
  const float* W       = (const float*)d_in[1];
  const float* att_src = (const float*)d_in[2];
  const float* att_dst = (const float*)d_in[3];
  const float* bias    = (const float*)d_in[4];
  float* out = (float*)d_out;

  char* ws = (char*)d_ws;
  // ws_size = 256 MiB; clean non-aliased layout (~72 MB):
  _Float16*     yf    = (_Float16*)    (ws + 0);           // 16 MB [prep_y..ht]
  _Float16*     htf   = (_Float16*)    (ws + 16777216);    // 16 MB [ht..pv]
  _Float16*     Pf    = (_Float16*)    (ws + 33554432);    // 32 MB [softmax..pv]
  uint16_t*     Mbits = (uint16_t*)    (ws + 67108864);    //  2 MB [sim..softmax]
  _Float16*     Wf    = (_Float16*)    (ws + 69206016);    // 512 KB [prep_w2..ht]
  float*        watt_s= (float*)       (ws + 69730304);    //  2 KB
  float*        watt_d= (float*)       (ws + 69732352);    //  2 KB
  float*        rnorm = (float*)       (ws + 69734400);    // 64 KB
  float*        a_src = (float*)       (ws + 69799936);    // 64 KB
  float*        a_dst = (float*)       (ws + 69865472);    // 64 KB
  unsigned int* list  = (unsigned int*)(ws + 69931008);    //  2 MB [sim..recheck]
  int*          cnt   = (int*)         (ws + 72028160);    // 64 B

  k_prep_w2   <<<dim3(34),   dim3(256), 0, stream>>>(W, att_src, att_dst, Wf, watt_s, watt_d);
  k_prep_y    <<<dim3(256),  dim3(256), 0, stream>>>(x, yf, rnorm, a_src, a_dst, watt_s, watt_d, cnt);
  k_sim_mfma  <<<dim3(576),  dim3(256), 0, stream>>>(yf, Mbits, list, cnt);
  k_ht_recheck<<<dim3(768),  dim3(256), 0, stream>>>(Wf, yf, x, rnorm, htf, (uint32_t*)Mbits, list, cnt);
  k_softmax   <<<dim3(4096), dim3(256), 0, stream>>>((const uint32_t*)Mbits, a_src, a_dst, Pf);
  k_pv        <<<dim3(512),  dim3(256), 0, stream>>>(Pf, htf, bias, out);
}

// Round 18
// 115.943 us; speedup vs baseline: 1.2664x; 1.1307x over previous
//
#include <hip/hip_runtime.h>
#include <hip/hip_bf16.h>
#include <stdint.h>

#define NB 16
#define NS 1024
#define ND 512
#define NO 512
#define NROW (NB*NS)   // 16384
#define SIM_BAND 1.5e-3f
#define LIST_CAP 524288

typedef float f32x4 __attribute__((ext_vector_type(4)));
typedef _Float16 f16x8 __attribute__((ext_vector_type(8)));

// ---------------- K1: merged W-prep: blocks 0..31 = Wf frag tiles (f16), 32..33 = watt ----------------
__global__ __launch_bounds__(256) void k_prep_w2(const float* __restrict__ W,
                                                 const float* __restrict__ att_src,
                                                 const float* __restrict__ att_dst,
                                                 _Float16* __restrict__ Wf,
                                                 float* __restrict__ watt_s,
                                                 float* __restrict__ watt_d) {
  __shared__ float as_[512], ad_[512];
  int blk = blockIdx.x, tid = threadIdx.x;
  if (blk < 32) {
    int mt = blk>>3, k0c = blk&7;
    size_t base = ((size_t)(mt*8 + k0c))*8192;
    #pragma unroll
    for (int pp = 0; pp < 4; ++pp) {
      int id = pp*256 + tid;
      int kb = id>>9, m = (id>>6)&7, g = (id>>4)&3, r = id&15;
      int o = mt*128 + m*16 + r;
      int d0 = k0c*64 + kb*32 + g*8;
      union { _Float16 h[8]; uint4 u; } pk;
      #pragma unroll
      for (int j = 0; j < 8; ++j) pk.h[j] = (_Float16)W[(size_t)(d0+j)*NO + o];
      *(uint4*)&Wf[base + id*8] = pk.u;
    }
  } else {
    as_[tid] = att_src[tid]; as_[tid+256] = att_src[tid+256];
    ad_[tid] = att_dst[tid]; ad_[tid+256] = att_dst[tid+256];
    __syncthreads();
    int d = (blk-32)*256 + tid;
    const float* wr = W + (size_t)d*NO;
    float s = 0.f, dd = 0.f;
    for (int o = 0; o < NO; o += 4) {
      float4 w = *(const float4*)&wr[o];
      s  = fmaf(w.x, as_[o], fmaf(w.y, as_[o+1], fmaf(w.z, as_[o+2], fmaf(w.w, as_[o+3], s))));
      dd = fmaf(w.x, ad_[o], fmaf(w.y, ad_[o+1], fmaf(w.z, ad_[o+2], fmaf(w.w, ad_[o+3], dd))));
    }
    watt_s[d] = s;
    watt_d[d] = dd;
  }
}

// ---------------- K2: rnorm + a_src/a_dst (via watt) + yf = f16(x*rn) fragment-order ----------------
__global__ __launch_bounds__(256) void k_prep_y(const float* __restrict__ x,
                                                _Float16* __restrict__ yf,
                                                float* __restrict__ rnorm,
                                                float* __restrict__ a_src,
                                                float* __restrict__ a_dst,
                                                const float* __restrict__ watt_s,
                                                const float* __restrict__ watt_d,
                                                int* __restrict__ counter) {
  __shared__ float ws_[512], wd_[512];
  int tid = threadIdx.x, blk = blockIdx.x;
  if (blk == 0 && tid == 0) *counter = 0;
  ws_[tid] = watt_s[tid]; ws_[tid+256] = watt_s[tid+256];
  wd_[tid] = watt_d[tid]; wd_[tid+256] = watt_d[tid+256];
  __syncthreads();
  int r = tid>>2, q = tid&3;
  int grow = blk*64 + r;
  const float* xr = x + (size_t)grow*ND + q*128;
  float ssq = 0.f, as = 0.f, ad = 0.f;
  #pragma unroll
  for (int c8 = 0; c8 < 16; ++c8) {
    float4 v0 = *(const float4*)&xr[c8*8];
    float4 v1 = *(const float4*)&xr[c8*8+4];
    float vv[8] = {v0.x,v0.y,v0.z,v0.w,v1.x,v1.y,v1.z,v1.w};
    #pragma unroll
    for (int j = 0; j < 8; ++j) {
      int c = q*128 + c8*8 + j;
      ssq = fmaf(vv[j], vv[j], ssq);
      as  = fmaf(vv[j], ws_[c], as);
      ad  = fmaf(vv[j], wd_[c], ad);
    }
  }
  ssq += __shfl_xor(ssq, 1, 64); ssq += __shfl_xor(ssq, 2, 64);
  as  += __shfl_xor(as, 1, 64);  as  += __shfl_xor(as, 2, 64);
  ad  += __shfl_xor(ad, 1, 64);  ad  += __shfl_xor(ad, 2, 64);
  float rn = 1.0f / fmaxf(sqrtf(ssq), 1e-12f);
  if (q == 0) { rnorm[grow] = rn; a_src[grow] = as; a_dst[grow] = ad; }
  int trow = grow & (NS-1), b = grow >> 10;
  int m = (trow>>4)&7, rr = trow&15;
  size_t tilebase = ((size_t)(b*8 + (trow>>7)))*65536;
  #pragma unroll
  for (int c8 = 0; c8 < 16; ++c8) {
    int col = q*128 + c8*8;
    int k0c = col>>6, cc = col&63, kb = cc>>5, g = (cc>>3)&3;
    int id = kb*512 + m*64 + g*16 + rr;
    size_t off = tilebase + (size_t)k0c*8192 + id*8;
    float4 v0 = *(const float4*)&xr[c8*8];
    float4 v1 = *(const float4*)&xr[c8*8+4];
    float vv[8] = {v0.x,v0.y,v0.z,v0.w,v1.x,v1.y,v1.z,v1.w};
    union { _Float16 h[8]; uint4 u; } pk;
    #pragma unroll
    for (int j = 0; j < 8; ++j) pk.h[j] = (_Float16)(vv[j]*rn);   // RTN f16
    *(uint4*)&yf[off] = pk.u;
  }
}

// ---------------- K3 (fused): blocks 0..575 = sim -> bits+list; 576..1087 = gemm_ht ----------------
__global__ __launch_bounds__(256) void k_sim_ht(const _Float16* __restrict__ yf,
                                                const _Float16* __restrict__ Wf,
                                                const float* __restrict__ rnorm,
                                                uint16_t* __restrict__ Mbits,
                                                unsigned int* __restrict__ list,
                                                int* __restrict__ counter,
                                                _Float16* __restrict__ htf) {
  __shared__ __align__(16) _Float16 sbuf[16384];   // used only by ht path (output staging)
  int bid0 = blockIdx.x;
  int tid = threadIdx.x, wid = tid>>6, lane = tid&63;
  int wm = (wid>>1)*64, wn = (wid&1)*64;
  int aq = (wm>>4), bq = (wn>>4);
  if (bid0 < 576) {
    // ---- sim path (zero-LDS fragment streaming, r17-proven) ----
    int swz = (bid0 & 7)*72 + (bid0 >> 3);      // bijective: 576 = 8*72
    int b = swz / 36, p = swz - b*36;
    int ti = 0;
    while ((ti+1)*(ti+2)/2 <= p) ++ti;
    int tj = p - ti*(ti+1)/2;                   // tj <= ti
    size_t Abase = ((size_t)(b*8+ti))*65536 + (size_t)lane*8;
    size_t Bbase = ((size_t)(b*8+tj))*65536 + (size_t)lane*8;
    f32x4 acc[4][4] = {};
    for (int k0c = 0; k0c < 8; ++k0c) {
      #pragma unroll
      for (int kb = 0; kb < 2; ++kb) {
        f16x8 ah[4], bh[4];
        #pragma unroll
        for (int q = 0; q < 4; ++q) {
          ah[q] = *(const f16x8*)&yf[Abase + (size_t)k0c*8192 + (size_t)(kb*8 + aq + q)*512];
          bh[q] = *(const f16x8*)&yf[Bbase + (size_t)k0c*8192 + (size_t)(kb*8 + bq + q)*512];
        }
        #pragma unroll
        for (int mi = 0; mi < 4; ++mi)
          #pragma unroll
          for (int ni = 0; ni < 4; ++ni)
            acc[mi][ni] = __builtin_amdgcn_mfma_f32_16x16x32_f16(ah[mi], bh[ni], acc[mi][ni], 0,0,0);
      }
    }
    int hi = lane>>4, colL = lane&15;
    #pragma unroll
    for (int mi = 0; mi < 4; ++mi) {
      #pragma unroll
      for (int r2 = 0; r2 < 4; ++r2) {
        int t_g = ti*128 + wm + mi*16 + hi*4 + r2;
        int git = b*NS + t_g;
        #pragma unroll
        for (int ni = 0; ni < 4; ++ni) {
          int s_g = tj*128 + wn + ni*16 + colL;
          float sim = acc[mi][ni][r2];
          bool bit = (s_g == t_g) || (s_g < t_g && sim > 0.9f);
          // wave-aggregated borderline append (64x fewer atomics)
          bool cond = (s_g < t_g) && (fabsf(sim - 0.9f) <= SIM_BAND);
          unsigned long long bb = __ballot(cond);
          if (bb) {
            int leader = __ffsll((unsigned long long)bb) - 1;
            int base = 0;
            if (lane == leader) base = atomicAdd(counter, __popcll(bb));
            base = __shfl(base, leader, 64);
            if (cond) {
              int idx = base + __popcll(bb & ((1ULL<<lane)-1ULL));
              if (idx < LIST_CAP) list[idx] = ((unsigned)b<<20) | ((unsigned)t_g<<10) | (unsigned)s_g;
            }
          }
          unsigned long long bal = __ballot(bit);
          if (colL == 0) {
            uint16_t slice = (uint16_t)((bal >> (hi*16)) & 0xFFFFull);
            Mbits[(size_t)git*64 + ((tj*128 + wn + ni*16)>>4)] = slice;
          }
        }
      }
    }
  } else {
    // ---- gemm_ht path (zero-LDS loop + LDS-staged coalesced output, r17-proven) ----
    int bidh = bid0 - 576;
    int swz = (bidh&7)*64 + (bidh>>3);          // bijective: 512 = 8*64
    int mt = swz&3, it = swz>>2;
    int b = it>>3, tblk = it&7;
    size_t Abase = ((size_t)mt)*65536 + (size_t)lane*8;
    size_t Bbase = ((size_t)(b*8+tblk))*65536 + (size_t)lane*8;
    f32x4 acc[4][4] = {};
    for (int k0c = 0; k0c < 8; ++k0c) {
      #pragma unroll
      for (int kb = 0; kb < 2; ++kb) {
        f16x8 a[4], bb2[4];
        #pragma unroll
        for (int q = 0; q < 4; ++q) {
          a  [q] = *(const f16x8*)&Wf[Abase + (size_t)k0c*8192 + (size_t)(kb*8 + aq + q)*512];
          bb2[q] = *(const f16x8*)&yf[Bbase + (size_t)k0c*8192 + (size_t)(kb*8 + bq + q)*512];
        }
        #pragma unroll
        for (int mi = 0; mi < 4; ++mi)
          #pragma unroll
          for (int ni = 0; ni < 4; ++ni)
            acc[mi][ni] = __builtin_amdgcn_mfma_f32_16x16x32_f16(a[mi], bb2[ni], acc[mi][ni], 0,0,0);
      }
    }
    {
      int rbase = (lane>>4)*4, colL = lane&15;
      #pragma unroll
      for (int ni = 0; ni < 4; ++ni) {
        int i_local = wn + ni*16 + colL;
        int gn = it*128 + i_local;
        float xn = 1.0f / rnorm[gn];
        int tsel = i_local>>6, ic = i_local&63;
        int kb = ic>>5, g = (ic>>3)&3, j = ic&7;
        int base = tsel*8192 + (kb*512 + g*16)*8 + j;
        #pragma unroll
        for (int mi = 0; mi < 4; ++mi)
          #pragma unroll
          for (int r2 = 0; r2 < 4; ++r2) {
            int o_local = wm + mi*16 + rbase + r2;
            int m = o_local>>4, r = o_local&15;
            sbuf[base + (m*64 + r)*8] = (_Float16)(acc[mi][ni][r2] * xn);
          }
      }
    }
    __syncthreads();
    {
      size_t gbase = ((size_t)((mt*NB + b)*16 + tblk*2))*8192;
      const uint4* src = (const uint4*)sbuf;
      uint4* dst = (uint4*)(htf + gbase);
      #pragma unroll
      for (int k = 0; k < 8; ++k) dst[tid + k*256] = src[tid + k*256];
    }
  }
}

// ---------------- K4: WAVE-COOPERATIVE exact f32 recheck of borderline pairs ----------------
__global__ __launch_bounds__(256) void k_recheck(const float* __restrict__ x,
                                                 const float* __restrict__ rnorm,
                                                 uint32_t* __restrict__ Mw,
                                                 const unsigned int* __restrict__ list,
                                                 const int* __restrict__ counter) {
  int n = *counter;
  if (n > LIST_CAP) n = LIST_CAP;
  int lane = threadIdx.x & 63;
  int gwave = blockIdx.x*4 + (threadIdx.x>>6);   // grid 2048 -> 8192 waves
  for (int p = gwave; p < n; p += 8192) {
    unsigned v = list[p];
    int b = v>>20, t = (v>>10)&1023, s = v&1023;
    const float* xt = x + ((size_t)(b*NS + t))*ND + lane*8;
    const float* xs = x + ((size_t)(b*NS + s))*ND + lane*8;
    float4 t0 = *(const float4*)xt;
    float4 t1 = *(const float4*)(xt+4);
    float4 s0 = *(const float4*)xs;
    float4 s1 = *(const float4*)(xs+4);
    float d = 0.f;
    d = fmaf(t0.x,s0.x, fmaf(t0.y,s0.y, fmaf(t0.z,s0.z, fmaf(t0.w,s0.w, d))));
    d = fmaf(t1.x,s1.x, fmaf(t1.y,s1.y, fmaf(t1.z,s1.z, fmaf(t1.w,s1.w, d))));
    #pragma unroll
    for (int off = 32; off > 0; off >>= 1) d += __shfl_xor(d, off, 64);
    if (lane == 0) {
      float sim = d * rnorm[b*NS+t] * rnorm[b*NS+s];
      int git = b*NS + t;
      uint32_t bmask = 1u << (s&31);
      if (sim > 0.9f) atomicOr (&Mw[(size_t)git*32 + (s>>5)], bmask);
      else            atomicAnd(&Mw[(size_t)git*32 + (s>>5)], ~bmask);
    }
  }
}

// ---------------- K5: masked softmax (bit mask) -> Pf (f16 frag-order), LDS-staged writes ----------
__global__ __launch_bounds__(256) void k_softmax(const uint32_t* __restrict__ Mw,
                                                 const float* __restrict__ a_src,
                                                 const float* __restrict__ a_dst,
                                                 _Float16* __restrict__ Pf) {
  __shared__ __align__(16) _Float16 pbuf[4][1032];
  int wid = threadIdx.x>>6, lane = threadIdx.x&63;
  int rowid = blockIdx.x*4 + wid;
  int t = rowid & (NS-1), b = rowid >> 10;
  int n = t + 1;
  const float* as = a_src + b*NS;
  float adv = a_dst[rowid];
  uint32_t w = Mw[(size_t)rowid*32 + (lane>>1)];
  uint32_t bits16 = (lane&1) ? (w>>16) : (w & 0xFFFFu);
  int s0 = lane*16;
  float4 a0 = *(const float4*)&as[s0];
  float4 a1 = *(const float4*)&as[s0+4];
  float4 a2 = *(const float4*)&as[s0+8];
  float4 a3 = *(const float4*)&as[s0+12];
  float va[16] = {a0.x,a0.y,a0.z,a0.w, a1.x,a1.y,a1.z,a1.w,
                  a2.x,a2.y,a2.z,a2.w, a3.x,a3.y,a3.z,a3.w};
  float pr[16];
  float lm = -INFINITY;
  #pragma unroll
  for (int k = 0; k < 16; ++k) {
    int s = s0 + k;
    bool on = (s < n) && ((bits16>>k)&1);
    float vv = adv + va[k];
    float v = (vv > 0.f) ? vv : 0.2f*vv;
    pr[k] = on ? v : -INFINITY;
    lm = fmaxf(lm, pr[k]);
  }
  #pragma unroll
  for (int off = 32; off > 0; off >>= 1) lm = fmaxf(lm, __shfl_xor(lm, off, 64));
  float ls = 0.f;
  #pragma unroll
  for (int k = 0; k < 16; ++k) { pr[k] = __expf(pr[k] - lm); ls += pr[k]; }
  #pragma unroll
  for (int off = 32; off > 0; off >>= 1) ls += __shfl_xor(ls, off, 64);
  float inv = 1.0f / ls;
  union { _Float16 hh[8]; uint4 u; } pk0, pk1;
  #pragma unroll
  for (int j = 0; j < 8; ++j) pk0.hh[j] = (_Float16)(pr[j]*inv);
  #pragma unroll
  for (int j = 0; j < 8; ++j) pk1.hh[j] = (_Float16)(pr[8+j]*inv);
  *(uint4*)&pbuf[wid][s0]   = pk0.u;
  *(uint4*)&pbuf[wid][s0+8] = pk1.u;
  __syncthreads();
  int t0 = (blockIdx.x*4) & (NS-1);
  int b0 = (blockIdx.x*4) >> 10;
  int end = ((t0 >> 7) + 1) << 7;
  int m = (t0>>4)&7, r0 = t0&15;
  size_t tbase = ((size_t)(b0*8 + (t0>>7)))*131072;
  int nslots = (end>>3)*4;
  for (int u = threadIdx.x; u < nslots; u += 256) {
    int rr = u&3, c8 = u>>2;
    int icol = c8*8;
    int k0c = icol>>6, kb = (icol>>5)&1, g = (icol>>3)&3;
    uint4 v = *(const uint4*)&pbuf[rr][icol];
    *(uint4*)&Pf[tbase + (size_t)k0c*8192 + (size_t)(kb*512 + m*64 + g*16 + r0 + rr)*8] = v;
  }
}

// ---------------- K6: out = relu(P @ h + bias) -- zero-LDS fragment streaming, causal ----------------
__global__ __launch_bounds__(256) void k_pv(const _Float16* __restrict__ Pf,
                                            const _Float16* __restrict__ htf,
                                            const float* __restrict__ bias,
                                            float* __restrict__ out) {
  int bid = blockIdx.x;
  int swz = (bid&7)*64 + (bid>>3);          // bijective: 512 = 8*64
  int b = swz>>5, rem = swz&31, mt = rem>>2, nt = rem&3;
  int tid = threadIdx.x, wid = tid>>6, lane = tid&63;
  int wm = (wid>>1)*64, wn = (wid&1)*64;
  size_t Abase = ((size_t)((b*8 + mt)*16))*8192 + (size_t)lane*8;
  size_t Bbase = ((size_t)((nt*NB + b)*16))*8192 + (size_t)lane*8;
  int aq = (wm>>4), bq = (wn>>4);
  f32x4 acc[4][4] = {};
  int nk0 = 2*(mt+1);
  for (int k0c = 0; k0c < nk0; ++k0c) {
    #pragma unroll
    for (int kb = 0; kb < 2; ++kb) {
      f16x8 a[4], bb[4];
      #pragma unroll
      for (int q = 0; q < 4; ++q) {
        a [q] = *(const f16x8*)&Pf [Abase + (size_t)k0c*8192 + (size_t)(kb*8 + aq + q)*512];
        bb[q] = *(const f16x8*)&htf[Bbase + (size_t)k0c*8192 + (size_t)(kb*8 + bq + q)*512];
      }
      #pragma unroll
      for (int mi = 0; mi < 4; ++mi)
        #pragma unroll
        for (int ni = 0; ni < 4; ++ni)
          acc[mi][ni] = __builtin_amdgcn_mfma_f32_16x16x32_f16(a[mi], bb[ni], acc[mi][ni], 0,0,0);
    }
  }
  int m0 = mt*128, n0 = nt*128;
  int rbase = (lane>>4)*4, col = lane&15;
  #pragma unroll
  for (int mi = 0; mi < 4; ++mi)
    #pragma unroll
    for (int ni = 0; ni < 4; ++ni) {
      int gm = m0 + wm + mi*16 + rbase;
      int gn = n0 + wn + ni*16 + col;
      float bv = bias[gn];
      #pragma unroll
      for (int r2 = 0; r2 < 4; ++r2)
        out[((size_t)b*NS + gm + r2)*NO + gn] = fmaxf(acc[mi][ni][r2] + bv, 0.0f);
    }
}

extern "C" void kernel_launch(void* const* d_in, const int* in_sizes, int n_in,
                              void* d_out, int out_size, void* d_ws, size_t ws_size,
                              hipStream_t stream) {
  (void)in_sizes; (void)n_in; (void)out_size; (void)ws_size;
  const float* x       = (const float*)d_in[0];
  const float* W       = (const float*)d_in[1];
  const float* att_src = (const float*)d_in[2];
  const float* att_dst = (const float*)d_in[3];
  const float* bias    = (const float*)d_in[4];
  float* out = (float*)d_out;

  char* ws = (char*)d_ws;
  _Float16*     yf    = (_Float16*)    (ws + 0);           // 16 MB [prep_y..sim_ht]
  _Float16*     htf   = (_Float16*)    (ws + 16777216);    // 16 MB [sim_ht..pv]
  _Float16*     Pf    = (_Float16*)    (ws + 33554432);    // 32 MB [softmax..pv]
  uint16_t*     Mbits = (uint16_t*)    (ws + 67108864);    //  2 MB [sim_ht..softmax]
  _Float16*     Wf    = (_Float16*)    (ws + 69206016);    // 512 KB [prep_w2..sim_ht]
  float*        watt_s= (float*)       (ws + 69730304);    //  2 KB
  float*        watt_d= (float*)       (ws + 69732352);    //  2 KB
  float*        rnorm = (float*)       (ws + 69734400);    // 64 KB
  float*        a_src = (float*)       (ws + 69799936);    // 64 KB
  float*        a_dst = (float*)       (ws + 69865472);    // 64 KB
  unsigned int* list  = (unsigned int*)(ws + 69931008);    //  2 MB [sim_ht..recheck]
  int*          cnt   = (int*)         (ws + 72028160);    // 64 B

  k_prep_w2<<<dim3(34),   dim3(256), 0, stream>>>(W, att_src, att_dst, Wf, watt_s, watt_d);
  k_prep_y <<<dim3(256),  dim3(256), 0, stream>>>(x, yf, rnorm, a_src, a_dst, watt_s, watt_d, cnt);
  k_sim_ht <<<dim3(1088), dim3(256), 0, stream>>>(yf, Wf, rnorm, Mbits, list, cnt, htf);
  k_recheck<<<dim3(2048), dim3(256), 0, stream>>>(x, rnorm, (uint32_t*)Mbits, list, cnt);
  k_softmax<<<dim3(4096), dim3(256), 0, stream>>>((const uint32_t*)Mbits, a_src, a_dst, Pf);
  k_pv     <<<dim3(512),  dim3(256), 0, stream>>>(Pf, htf, bias, out);
}

// Round 19
// 107.649 us; speedup vs baseline: 1.3640x; 1.0770x over previous
//
#include <hip/hip_runtime.h>
#include <hip/hip_bf16.h>
#include <stdint.h>

#define NB 16
#define NS 1024
#define ND 512
#define NO 512
#define NROW (NB*NS)   // 16384
#define SIM_BAND 1.5e-3f
#define LIST_CAP 524288

typedef float f32x4 __attribute__((ext_vector_type(4)));
typedef _Float16 f16x8 __attribute__((ext_vector_type(8)));

// ---------------- K1: merged W-prep: blocks 0..31 = Wf frag tiles (f16), 32..33 = watt ----------------
__global__ __launch_bounds__(256) void k_prep_w2(const float* __restrict__ W,
                                                 const float* __restrict__ att_src,
                                                 const float* __restrict__ att_dst,
                                                 _Float16* __restrict__ Wf,
                                                 float* __restrict__ watt_s,
                                                 float* __restrict__ watt_d) {
  __shared__ float as_[512], ad_[512];
  int blk = blockIdx.x, tid = threadIdx.x;
  if (blk < 32) {
    int mt = blk>>3, k0c = blk&7;
    size_t base = ((size_t)(mt*8 + k0c))*8192;
    #pragma unroll
    for (int pp = 0; pp < 4; ++pp) {
      int id = pp*256 + tid;
      int kb = id>>9, m = (id>>6)&7, g = (id>>4)&3, r = id&15;
      int o = mt*128 + m*16 + r;
      int d0 = k0c*64 + kb*32 + g*8;
      union { _Float16 h[8]; uint4 u; } pk;
      #pragma unroll
      for (int j = 0; j < 8; ++j) pk.h[j] = (_Float16)W[(size_t)(d0+j)*NO + o];
      *(uint4*)&Wf[base + id*8] = pk.u;
    }
  } else {
    as_[tid] = att_src[tid]; as_[tid+256] = att_src[tid+256];
    ad_[tid] = att_dst[tid]; ad_[tid+256] = att_dst[tid+256];
    __syncthreads();
    int d = (blk-32)*256 + tid;
    const float* wr = W + (size_t)d*NO;
    float s = 0.f, dd = 0.f;
    for (int o = 0; o < NO; o += 4) {
      float4 w = *(const float4*)&wr[o];
      s  = fmaf(w.x, as_[o], fmaf(w.y, as_[o+1], fmaf(w.z, as_[o+2], fmaf(w.w, as_[o+3], s))));
      dd = fmaf(w.x, ad_[o], fmaf(w.y, ad_[o+1], fmaf(w.z, ad_[o+2], fmaf(w.w, ad_[o+3], dd))));
    }
    watt_s[d] = s;
    watt_d[d] = dd;
  }
}

// ---------------- K2: rnorm + a_src/a_dst (via watt) + yf = f16(x*rn) fragment-order ----------------
__global__ __launch_bounds__(256) void k_prep_y(const float* __restrict__ x,
                                                _Float16* __restrict__ yf,
                                                float* __restrict__ rnorm,
                                                float* __restrict__ a_src,
                                                float* __restrict__ a_dst,
                                                const float* __restrict__ watt_s,
                                                const float* __restrict__ watt_d,
                                                int* __restrict__ counter) {
  __shared__ float ws_[512], wd_[512];
  int tid = threadIdx.x, blk = blockIdx.x;
  if (blk == 0 && tid == 0) *counter = 0;
  ws_[tid] = watt_s[tid]; ws_[tid+256] = watt_s[tid+256];
  wd_[tid] = watt_d[tid]; wd_[tid+256] = watt_d[tid+256];
  __syncthreads();
  int r = tid>>2, q = tid&3;
  int grow = blk*64 + r;
  const float* xr = x + (size_t)grow*ND + q*128;
  float ssq = 0.f, as = 0.f, ad = 0.f;
  #pragma unroll
  for (int c8 = 0; c8 < 16; ++c8) {
    float4 v0 = *(const float4*)&xr[c8*8];
    float4 v1 = *(const float4*)&xr[c8*8+4];
    float vv[8] = {v0.x,v0.y,v0.z,v0.w,v1.x,v1.y,v1.z,v1.w};
    #pragma unroll
    for (int j = 0; j < 8; ++j) {
      int c = q*128 + c8*8 + j;
      ssq = fmaf(vv[j], vv[j], ssq);
      as  = fmaf(vv[j], ws_[c], as);
      ad  = fmaf(vv[j], wd_[c], ad);
    }
  }
  ssq += __shfl_xor(ssq, 1, 64); ssq += __shfl_xor(ssq, 2, 64);
  as  += __shfl_xor(as, 1, 64);  as  += __shfl_xor(as, 2, 64);
  ad  += __shfl_xor(ad, 1, 64);  ad  += __shfl_xor(ad, 2, 64);
  float rn = 1.0f / fmaxf(sqrtf(ssq), 1e-12f);
  if (q == 0) { rnorm[grow] = rn; a_src[grow] = as; a_dst[grow] = ad; }
  int trow = grow & (NS-1), b = grow >> 10;
  int m = (trow>>4)&7, rr = trow&15;
  size_t tilebase = ((size_t)(b*8 + (trow>>7)))*65536;
  #pragma unroll
  for (int c8 = 0; c8 < 16; ++c8) {
    int col = q*128 + c8*8;
    int k0c = col>>6, cc = col&63, kb = cc>>5, g = (cc>>3)&3;
    int id = kb*512 + m*64 + g*16 + rr;
    size_t off = tilebase + (size_t)k0c*8192 + id*8;
    float4 v0 = *(const float4*)&xr[c8*8];
    float4 v1 = *(const float4*)&xr[c8*8+4];
    float vv[8] = {v0.x,v0.y,v0.z,v0.w,v1.x,v1.y,v1.z,v1.w};
    union { _Float16 h[8]; uint4 u; } pk;
    #pragma unroll
    for (int j = 0; j < 8; ++j) pk.h[j] = (_Float16)(vv[j]*rn);   // RTN f16
    *(uint4*)&yf[off] = pk.u;
  }
}

// ---- zero-LDS fragment load (half h = k0c*2+kb covers 32 k-cols): frag = base + h*4096 + q*512 ----
#define FRAG_LD(AH, BH, APTR, BPTR, h) do { \
    _Pragma("unroll") \
    for (int q_ = 0; q_ < 4; ++q_) { \
      AH[q_] = *(const f16x8*)&APTR[Abase + (size_t)(h)*4096 + (size_t)(aq + q_)*512]; \
      BH[q_] = *(const f16x8*)&BPTR[Bbase + (size_t)(h)*4096 + (size_t)(bq + q_)*512]; \
    } \
  } while(0)

#define MFMA16(AH, BH) do { \
    _Pragma("unroll") \
    for (int mi_ = 0; mi_ < 4; ++mi_) \
      _Pragma("unroll") \
      for (int ni_ = 0; ni_ < 4; ++ni_) \
        acc[mi_][ni_] = __builtin_amdgcn_mfma_f32_16x16x32_f16(AH[mi_], BH[ni_], acc[mi_][ni_], 0,0,0); \
  } while(0)

// ---------------- K3 (fused): blocks 0..575 = sim -> bits+list; 576..1087 = gemm_ht ----------------
__global__ __launch_bounds__(256) void k_sim_ht(const _Float16* __restrict__ yf,
                                                const _Float16* __restrict__ Wf,
                                                const float* __restrict__ rnorm,
                                                uint16_t* __restrict__ Mbits,
                                                unsigned int* __restrict__ list,
                                                int* __restrict__ counter,
                                                _Float16* __restrict__ htf) {
  __shared__ __align__(16) _Float16 sbuf[16384];   // used only by ht path (output staging)
  int bid0 = blockIdx.x;
  int tid = threadIdx.x, wid = tid>>6, lane = tid&63;
  int wm = (wid>>1)*64, wn = (wid&1)*64;
  int aq = (wm>>4), bq = (wn>>4);
  if (bid0 < 576) {
    // ---- sim path: zero-LDS with REGISTER double-buffer prefetch ----
    int swz = (bid0 & 7)*72 + (bid0 >> 3);      // bijective: 576 = 8*72
    int b = swz / 36, p = swz - b*36;
    int ti = 0;
    while ((ti+1)*(ti+2)/2 <= p) ++ti;
    int tj = p - ti*(ti+1)/2;                   // tj <= ti
    size_t Abase = ((size_t)(b*8+ti))*65536 + (size_t)lane*8;
    size_t Bbase = ((size_t)(b*8+tj))*65536 + (size_t)lane*8;
    f32x4 acc[4][4] = {};
    f16x8 A0[4], B0[4], A1[4], B1[4];
    FRAG_LD(A0, B0, yf, yf, 0);
    for (int hp = 0; hp < 8; ++hp) {
      FRAG_LD(A1, B1, yf, yf, 2*hp+1);
      MFMA16(A0, B0);
      if (hp < 7) FRAG_LD(A0, B0, yf, yf, 2*hp+2);
      MFMA16(A1, B1);
    }
    int hi = lane>>4, colL = lane&15;
    #pragma unroll
    for (int mi = 0; mi < 4; ++mi) {
      #pragma unroll
      for (int r2 = 0; r2 < 4; ++r2) {
        int t_g = ti*128 + wm + mi*16 + hi*4 + r2;
        int git = b*NS + t_g;
        #pragma unroll
        for (int ni = 0; ni < 4; ++ni) {
          int s_g = tj*128 + wn + ni*16 + colL;
          float sim = acc[mi][ni][r2];
          bool bit = (s_g == t_g) || (s_g < t_g && sim > 0.9f);
          bool cond = (s_g < t_g) && (fabsf(sim - 0.9f) <= SIM_BAND);
          unsigned long long bb = __ballot(cond);
          if (bb) {
            int leader = __ffsll((unsigned long long)bb) - 1;
            int base = 0;
            if (lane == leader) base = atomicAdd(counter, __popcll(bb));
            base = __shfl(base, leader, 64);
            if (cond) {
              int idx = base + __popcll(bb & ((1ULL<<lane)-1ULL));
              if (idx < LIST_CAP) list[idx] = ((unsigned)b<<20) | ((unsigned)t_g<<10) | (unsigned)s_g;
            }
          }
          unsigned long long bal = __ballot(bit);
          if (colL == 0) {
            uint16_t slice = (uint16_t)((bal >> (hi*16)) & 0xFFFFull);
            Mbits[(size_t)git*64 + ((tj*128 + wn + ni*16)>>4)] = slice;
          }
        }
      }
    }
  } else {
    // ---- gemm_ht path: zero-LDS + register prefetch; LDS only for coalesced output ----
    int bidh = bid0 - 576;
    int swz = (bidh&7)*64 + (bidh>>3);          // bijective: 512 = 8*64
    int mt = swz&3, it = swz>>2;
    int b = it>>3, tblk = it&7;
    size_t Abase = ((size_t)mt)*65536 + (size_t)lane*8;
    size_t Bbase = ((size_t)(b*8+tblk))*65536 + (size_t)lane*8;
    f32x4 acc[4][4] = {};
    f16x8 A0[4], B0[4], A1[4], B1[4];
    FRAG_LD(A0, B0, Wf, yf, 0);
    for (int hp = 0; hp < 8; ++hp) {
      FRAG_LD(A1, B1, Wf, yf, 2*hp+1);
      MFMA16(A0, B0);
      if (hp < 7) FRAG_LD(A0, B0, Wf, yf, 2*hp+2);
      MFMA16(A1, B1);
    }
    {
      int rbase = (lane>>4)*4, colL = lane&15;
      #pragma unroll
      for (int ni = 0; ni < 4; ++ni) {
        int i_local = wn + ni*16 + colL;
        int gn = it*128 + i_local;
        float xn = 1.0f / rnorm[gn];
        int tsel = i_local>>6, ic = i_local&63;
        int kb = ic>>5, g = (ic>>3)&3, j = ic&7;
        int base = tsel*8192 + (kb*512 + g*16)*8 + j;
        #pragma unroll
        for (int mi = 0; mi < 4; ++mi)
          #pragma unroll
          for (int r2 = 0; r2 < 4; ++r2) {
            int o_local = wm + mi*16 + rbase + r2;
            int m = o_local>>4, r = o_local&15;
            sbuf[base + (m*64 + r)*8] = (_Float16)(acc[mi][ni][r2] * xn);
          }
      }
    }
    __syncthreads();
    {
      size_t gbase = ((size_t)((mt*NB + b)*16 + tblk*2))*8192;
      const uint4* src = (const uint4*)sbuf;
      uint4* dst = (uint4*)(htf + gbase);
      #pragma unroll
      for (int k = 0; k < 8; ++k) dst[tid + k*256] = src[tid + k*256];
    }
  }
}

// ---------------- K4: WAVE-COOPERATIVE exact f32 recheck of borderline pairs ----------------
__global__ __launch_bounds__(256) void k_recheck(const float* __restrict__ x,
                                                 const float* __restrict__ rnorm,
                                                 uint32_t* __restrict__ Mw,
                                                 const unsigned int* __restrict__ list,
                                                 const int* __restrict__ counter) {
  int n = *counter;
  if (n > LIST_CAP) n = LIST_CAP;
  int lane = threadIdx.x & 63;
  int gwave = blockIdx.x*4 + (threadIdx.x>>6);   // grid 2048 -> 8192 waves
  for (int p = gwave; p < n; p += 8192) {
    unsigned v = list[p];
    int b = v>>20, t = (v>>10)&1023, s = v&1023;
    const float* xt = x + ((size_t)(b*NS + t))*ND + lane*8;
    const float* xs = x + ((size_t)(b*NS + s))*ND + lane*8;
    float4 t0 = *(const float4*)xt;
    float4 t1 = *(const float4*)(xt+4);
    float4 s0 = *(const float4*)xs;
    float4 s1 = *(const float4*)(xs+4);
    float d = 0.f;
    d = fmaf(t0.x,s0.x, fmaf(t0.y,s0.y, fmaf(t0.z,s0.z, fmaf(t0.w,s0.w, d))));
    d = fmaf(t1.x,s1.x, fmaf(t1.y,s1.y, fmaf(t1.z,s1.z, fmaf(t1.w,s1.w, d))));
    #pragma unroll
    for (int off = 32; off > 0; off >>= 1) d += __shfl_xor(d, off, 64);
    if (lane == 0) {
      float sim = d * rnorm[b*NS+t] * rnorm[b*NS+s];
      int git = b*NS + t;
      uint32_t bmask = 1u << (s&31);
      if (sim > 0.9f) atomicOr (&Mw[(size_t)git*32 + (s>>5)], bmask);
      else            atomicAnd(&Mw[(size_t)git*32 + (s>>5)], ~bmask);
    }
  }
}

// ---------------- K5: masked softmax (bit mask) -> Pf (f16 frag-order), LDS-staged writes ----------
__global__ __launch_bounds__(256) void k_softmax(const uint32_t* __restrict__ Mw,
                                                 const float* __restrict__ a_src,
                                                 const float* __restrict__ a_dst,
                                                 _Float16* __restrict__ Pf) {
  __shared__ __align__(16) _Float16 pbuf[4][1032];
  int wid = threadIdx.x>>6, lane = threadIdx.x&63;
  int rowid = blockIdx.x*4 + wid;
  int t = rowid & (NS-1), b = rowid >> 10;
  int n = t + 1;
  const float* as = a_src + b*NS;
  float adv = a_dst[rowid];
  uint32_t w = Mw[(size_t)rowid*32 + (lane>>1)];
  uint32_t bits16 = (lane&1) ? (w>>16) : (w & 0xFFFFu);
  int s0 = lane*16;
  float4 a0 = *(const float4*)&as[s0];
  float4 a1 = *(const float4*)&as[s0+4];
  float4 a2 = *(const float4*)&as[s0+8];
  float4 a3 = *(const float4*)&as[s0+12];
  float va[16] = {a0.x,a0.y,a0.z,a0.w, a1.x,a1.y,a1.z,a1.w,
                  a2.x,a2.y,a2.z,a2.w, a3.x,a3.y,a3.z,a3.w};
  float pr[16];
  float lm = -INFINITY;
  #pragma unroll
  for (int k = 0; k < 16; ++k) {
    int s = s0 + k;
    bool on = (s < n) && ((bits16>>k)&1);
    float vv = adv + va[k];
    float v = (vv > 0.f) ? vv : 0.2f*vv;
    pr[k] = on ? v : -INFINITY;
    lm = fmaxf(lm, pr[k]);
  }
  #pragma unroll
  for (int off = 32; off > 0; off >>= 1) lm = fmaxf(lm, __shfl_xor(lm, off, 64));
  float ls = 0.f;
  #pragma unroll
  for (int k = 0; k < 16; ++k) { pr[k] = __expf(pr[k] - lm); ls += pr[k]; }
  #pragma unroll
  for (int off = 32; off > 0; off >>= 1) ls += __shfl_xor(ls, off, 64);
  float inv = 1.0f / ls;
  union { _Float16 hh[8]; uint4 u; } pk0, pk1;
  #pragma unroll
  for (int j = 0; j < 8; ++j) pk0.hh[j] = (_Float16)(pr[j]*inv);
  #pragma unroll
  for (int j = 0; j < 8; ++j) pk1.hh[j] = (_Float16)(pr[8+j]*inv);
  *(uint4*)&pbuf[wid][s0]   = pk0.u;
  *(uint4*)&pbuf[wid][s0+8] = pk1.u;
  __syncthreads();
  int t0 = (blockIdx.x*4) & (NS-1);
  int b0 = (blockIdx.x*4) >> 10;
  int end = ((t0 >> 7) + 1) << 7;
  int m = (t0>>4)&7, r0 = t0&15;
  size_t tbase = ((size_t)(b0*8 + (t0>>7)))*131072;
  int nslots = (end>>3)*4;
  for (int u = threadIdx.x; u < nslots; u += 256) {
    int rr = u&3, c8 = u>>2;
    int icol = c8*8;
    int k0c = icol>>6, kb = (icol>>5)&1, g = (icol>>3)&3;
    uint4 v = *(const uint4*)&pbuf[rr][icol];
    *(uint4*)&Pf[tbase + (size_t)k0c*8192 + (size_t)(kb*512 + m*64 + g*16 + r0 + rr)*8] = v;
  }
}

// ---------------- K6: out = relu(P @ h + bias) -- zero-LDS + register prefetch, causal ----------------
__global__ __launch_bounds__(256) void k_pv(const _Float16* __restrict__ Pf,
                                            const _Float16* __restrict__ htf,
                                            const float* __restrict__ bias,
                                            float* __restrict__ out) {
  int bid = blockIdx.x;
  int swz = (bid&7)*64 + (bid>>3);          // bijective: 512 = 8*64
  int b = swz>>5, rem = swz&31, mt = rem>>2, nt = rem&3;
  int tid = threadIdx.x, wid = tid>>6, lane = tid&63;
  int wm = (wid>>1)*64, wn = (wid&1)*64;
  size_t Abase = ((size_t)((b*8 + mt)*16))*8192 + (size_t)lane*8;
  size_t Bbase = ((size_t)((nt*NB + b)*16))*8192 + (size_t)lane*8;
  int aq = (wm>>4), bq = (wn>>4);
  f32x4 acc[4][4] = {};
  int nhp = 2*(mt+1);                       // loop pairs of halves; total halves = 4*(mt+1)
  f16x8 A0[4], B0[4], A1[4], B1[4];
  FRAG_LD(A0, B0, Pf, htf, 0);
  for (int hp = 0; hp < nhp; ++hp) {
    FRAG_LD(A1, B1, Pf, htf, 2*hp+1);
    MFMA16(A0, B0);
    if (hp < nhp-1) FRAG_LD(A0, B0, Pf, htf, 2*hp+2);
    MFMA16(A1, B1);
  }
  int m0 = mt*128, n0 = nt*128;
  int rbase = (lane>>4)*4, col = lane&15;
  #pragma unroll
  for (int mi = 0; mi < 4; ++mi)
    #pragma unroll
    for (int ni = 0; ni < 4; ++ni) {
      int gm = m0 + wm + mi*16 + rbase;
      int gn = n0 + wn + ni*16 + col;
      float bv = bias[gn];
      #pragma unroll
      for (int r2 = 0; r2 < 4; ++r2)
        out[((size_t)b*NS + gm + r2)*NO + gn] = fmaxf(acc[mi][ni][r2] + bv, 0.0f);
    }
}

extern "C" void kernel_launch(void* const* d_in, const int* in_sizes, int n_in,
                              void* d_out, int out_size, void* d_ws, size_t ws_size,
                              hipStream_t stream) {
  (void)in_sizes; (void)n_in; (void)out_size; (void)ws_size;
  const float* x       = (const float*)d_in[0];
  const float* W       = (const float*)d_in[1];
  const float* att_src = (const float*)d_in[2];
  const float* att_dst = (const float*)d_in[3];
  const float* bias    = (const float*)d_in[4];
  float* out = (float*)d_out;

  char* ws = (char*)d_ws;
  _Float16*     yf    = (_Float16*)    (ws + 0);           // 16 MB [prep_y..sim_ht]
  _Float16*     htf   = (_Float16*)    (ws + 16777216);    // 16 MB [sim_ht..pv]
  _Float16*     Pf    = (_Float16*)    (ws + 33554432);    // 32 MB [softmax..pv]
  uint16_t*     Mbits = (uint16_t*)    (ws + 67108864);    //  2 MB [sim_ht..softmax]
  _Float16*     Wf    = (_Float16*)    (ws + 69206016);    // 512 KB [prep_w2..sim_ht]
  float*        watt_s= (float*)       (ws + 69730304);    //  2 KB
  float*        watt_d= (float*)       (ws + 69732352);    //  2 KB
  float*        rnorm = (float*)       (ws + 69734400);    // 64 KB
  float*        a_src = (float*)       (ws + 69799936);    // 64 KB
  float*        a_dst = (float*)       (ws + 69865472);    // 64 KB
  unsigned int* list  = (unsigned int*)(ws + 69931008);    //  2 MB [sim_ht..recheck]
  int*          cnt   = (int*)         (ws + 72028160);    // 64 B

  k_prep_w2<<<dim3(34),   dim3(256), 0, stream>>>(W, att_src, att_dst, Wf, watt_s, watt_d);
  k_prep_y <<<dim3(256),  dim3(256), 0, stream>>>(x, yf, rnorm, a_src, a_dst, watt_s, watt_d, cnt);
  k_sim_ht <<<dim3(1088), dim3(256), 0, stream>>>(yf, Wf, rnorm, Mbits, list, cnt, htf);
  k_recheck<<<dim3(2048), dim3(256), 0, stream>>>(x, rnorm, (uint32_t*)Mbits, list, cnt);
  k_softmax<<<dim3(4096), dim3(256), 0, stream>>>((const uint32_t*)Mbits, a_src, a_dst, Pf);
  k_pv     <<<dim3(512),  dim3(256), 0, stream>>>(Pf, htf, bias, out);
}

// Round 21
// 107.238 us; speedup vs baseline: 1.3692x; 1.0038x over previous
//
#include <hip/hip_runtime.h>
#include <hip/hip_bf16.h>
#include <stdint.h>

#define NB 16
#define NS 1024
#define ND 512
#define NO 512
#define NROW (NB*NS)   // 16384
#define SIM_BAND 1.5e-3f

typedef float f32x4 __attribute__((ext_vector_type(4)));
typedef _Float16 f16x8 __attribute__((ext_vector_type(8)));

// ---------------- K1: merged W-prep: blocks 0..31 = Wf frag tiles (f16), 32..33 = watt ----------------
__global__ __launch_bounds__(256) void k_prep_w2(const float* __restrict__ W,
                                                 const float* __restrict__ att_src,
                                                 const float* __restrict__ att_dst,
                                                 _Float16* __restrict__ Wf,
                                                 float* __restrict__ watt_s,
                                                 float* __restrict__ watt_d) {
  __shared__ float as_[512], ad_[512];
  int blk = blockIdx.x, tid = threadIdx.x;
  if (blk < 32) {
    int mt = blk>>3, k0c = blk&7;
    size_t base = ((size_t)(mt*8 + k0c))*8192;
    #pragma unroll
    for (int pp = 0; pp < 4; ++pp) {
      int id = pp*256 + tid;
      int kb = id>>9, m = (id>>6)&7, g = (id>>4)&3, r = id&15;
      int o = mt*128 + m*16 + r;
      int d0 = k0c*64 + kb*32 + g*8;
      union { _Float16 h[8]; uint4 u; } pk;
      #pragma unroll
      for (int j = 0; j < 8; ++j) pk.h[j] = (_Float16)W[(size_t)(d0+j)*NO + o];
      *(uint4*)&Wf[base + id*8] = pk.u;
    }
  } else {
    as_[tid] = att_src[tid]; as_[tid+256] = att_src[tid+256];
    ad_[tid] = att_dst[tid]; ad_[tid+256] = att_dst[tid+256];
    __syncthreads();
    int d = (blk-32)*256 + tid;
    const float* wr = W + (size_t)d*NO;
    float s = 0.f, dd = 0.f;
    for (int o = 0; o < NO; o += 4) {
      float4 w = *(const float4*)&wr[o];
      s  = fmaf(w.x, as_[o], fmaf(w.y, as_[o+1], fmaf(w.z, as_[o+2], fmaf(w.w, as_[o+3], s))));
      dd = fmaf(w.x, ad_[o], fmaf(w.y, ad_[o+1], fmaf(w.z, ad_[o+2], fmaf(w.w, ad_[o+3], dd))));
    }
    watt_s[d] = s;
    watt_d[d] = dd;
  }
}

// ---------------- K2: rnorm + a_src/a_dst (via watt) + yf = f16(x*rn) fragment-order ----------------
__global__ __launch_bounds__(256) void k_prep_y(const float* __restrict__ x,
                                                _Float16* __restrict__ yf,
                                                float* __restrict__ rnorm,
                                                float* __restrict__ a_src,
                                                float* __restrict__ a_dst,
                                                const float* __restrict__ watt_s,
                                                const float* __restrict__ watt_d) {
  __shared__ float ws_[512], wd_[512];
  int tid = threadIdx.x, blk = blockIdx.x;
  ws_[tid] = watt_s[tid]; ws_[tid+256] = watt_s[tid+256];
  wd_[tid] = watt_d[tid]; wd_[tid+256] = watt_d[tid+256];
  __syncthreads();
  int r = tid>>2, q = tid&3;
  int grow = blk*64 + r;
  const float* xr = x + (size_t)grow*ND + q*128;
  float ssq = 0.f, as = 0.f, ad = 0.f;
  #pragma unroll
  for (int c8 = 0; c8 < 16; ++c8) {
    float4 v0 = *(const float4*)&xr[c8*8];
    float4 v1 = *(const float4*)&xr[c8*8+4];
    float vv[8] = {v0.x,v0.y,v0.z,v0.w,v1.x,v1.y,v1.z,v1.w};
    #pragma unroll
    for (int j = 0; j < 8; ++j) {
      int c = q*128 + c8*8 + j;
      ssq = fmaf(vv[j], vv[j], ssq);
      as  = fmaf(vv[j], ws_[c], as);
      ad  = fmaf(vv[j], wd_[c], ad);
    }
  }
  ssq += __shfl_xor(ssq, 1, 64); ssq += __shfl_xor(ssq, 2, 64);
  as  += __shfl_xor(as, 1, 64);  as  += __shfl_xor(as, 2, 64);
  ad  += __shfl_xor(ad, 1, 64);  ad  += __shfl_xor(ad, 2, 64);
  float rn = 1.0f / fmaxf(sqrtf(ssq), 1e-12f);
  if (q == 0) { rnorm[grow] = rn; a_src[grow] = as; a_dst[grow] = ad; }
  int trow = grow & (NS-1), b = grow >> 10;
  int m = (trow>>4)&7, rr = trow&15;
  size_t tilebase = ((size_t)(b*8 + (trow>>7)))*65536;
  #pragma unroll
  for (int c8 = 0; c8 < 16; ++c8) {
    int col = q*128 + c8*8;
    int k0c = col>>6, cc = col&63, kb = cc>>5, g = (cc>>3)&3;
    int id = kb*512 + m*64 + g*16 + rr;
    size_t off = tilebase + (size_t)k0c*8192 + id*8;
    float4 v0 = *(const float4*)&xr[c8*8];
    float4 v1 = *(const float4*)&xr[c8*8+4];
    float vv[8] = {v0.x,v0.y,v0.z,v0.w,v1.x,v1.y,v1.z,v1.w};
    union { _Float16 h[8]; uint4 u; } pk;
    #pragma unroll
    for (int j = 0; j < 8; ++j) pk.h[j] = (_Float16)(vv[j]*rn);   // RTN f16
    *(uint4*)&yf[off] = pk.u;
  }
}

// ---- zero-LDS fragment load (half h covers 32 k-cols): frag = base + h*4096 + q*512 ----
#define FRAG_LD(AH, BH, APTR, BPTR, h) do { \
    _Pragma("unroll") \
    for (int q_ = 0; q_ < 4; ++q_) { \
      AH[q_] = *(const f16x8*)&APTR[Abase + (size_t)(h)*4096 + (size_t)(aq + q_)*512]; \
      BH[q_] = *(const f16x8*)&BPTR[Bbase + (size_t)(h)*4096 + (size_t)(bq + q_)*512]; \
    } \
  } while(0)

#define MFMA16(AH, BH) do { \
    _Pragma("unroll") \
    for (int mi_ = 0; mi_ < 4; ++mi_) \
      _Pragma("unroll") \
      for (int ni_ = 0; ni_ < 4; ++ni_) \
        acc[mi_][ni_] = __builtin_amdgcn_mfma_f32_16x16x32_f16(AH[mi_], BH[ni_], acc[mi_][ni_], 0,0,0); \
  } while(0)

// ---------------- K3 (fused): blocks 0..575 = sim -> Mbits+Bbits; 576..1087 = gemm_ht ----------------
__global__ __launch_bounds__(256) void k_sim_ht(const _Float16* __restrict__ yf,
                                                const _Float16* __restrict__ Wf,
                                                const float* __restrict__ rnorm,
                                                uint16_t* __restrict__ Mbits,
                                                uint16_t* __restrict__ Bbits,
                                                _Float16* __restrict__ htf) {
  __shared__ __align__(16) _Float16 sbuf[16384];   // used only by ht path (output staging)
  int bid0 = blockIdx.x;
  int tid = threadIdx.x, wid = tid>>6, lane = tid&63;
  int wm = (wid>>1)*64, wn = (wid&1)*64;
  int aq = (wm>>4), bq = (wn>>4);
  if (bid0 < 576) {
    // ---- sim path: zero-LDS with register double-buffer prefetch (r19-proven) ----
    int swz = (bid0 & 7)*72 + (bid0 >> 3);      // bijective: 576 = 8*72
    int b = swz / 36, p = swz - b*36;
    int ti = 0;
    while ((ti+1)*(ti+2)/2 <= p) ++ti;
    int tj = p - ti*(ti+1)/2;                   // tj <= ti
    size_t Abase = ((size_t)(b*8+ti))*65536 + (size_t)lane*8;
    size_t Bbase = ((size_t)(b*8+tj))*65536 + (size_t)lane*8;
    f32x4 acc[4][4] = {};
    f16x8 A0[4], B0[4], A1[4], B1[4];
    FRAG_LD(A0, B0, yf, yf, 0);
    for (int hp = 0; hp < 8; ++hp) {
      FRAG_LD(A1, B1, yf, yf, 2*hp+1);
      MFMA16(A0, B0);
      if (hp < 7) FRAG_LD(A0, B0, yf, yf, 2*hp+2);
      MFMA16(A1, B1);
    }
    int hi = lane>>4, colL = lane&15;
    #pragma unroll
    for (int mi = 0; mi < 4; ++mi) {
      #pragma unroll
      for (int r2 = 0; r2 < 4; ++r2) {
        int t_g = ti*128 + wm + mi*16 + hi*4 + r2;
        int git = b*NS + t_g;
        #pragma unroll
        for (int ni = 0; ni < 4; ++ni) {
          int s_g = tj*128 + wn + ni*16 + colL;
          float sim = acc[mi][ni][r2];
          bool bit  = (s_g == t_g) || (s_g < t_g && sim > 0.9f);
          bool cond = (s_g < t_g) && (fabsf(sim - 0.9f) <= SIM_BAND);
          unsigned long long bal = __ballot(bit);
          unsigned long long bb  = __ballot(cond);
          if (colL == 0) {
            int widx = (tj*128 + wn + ni*16)>>4;
            Mbits[(size_t)git*64 + widx] = (uint16_t)((bal >> (hi*16)) & 0xFFFFull);
            Bbits[(size_t)git*64 + widx] = (uint16_t)((bb  >> (hi*16)) & 0xFFFFull);
          }
        }
      }
    }
  } else {
    // ---- gemm_ht path: zero-LDS + register prefetch; LDS only for coalesced output ----
    int bidh = bid0 - 576;
    int swz = (bidh&7)*64 + (bidh>>3);          // bijective: 512 = 8*64
    int mt = swz&3, it = swz>>2;
    int b = it>>3, tblk = it&7;
    size_t Abase = ((size_t)mt)*65536 + (size_t)lane*8;
    size_t Bbase = ((size_t)(b*8+tblk))*65536 + (size_t)lane*8;
    f32x4 acc[4][4] = {};
    f16x8 A0[4], B0[4], A1[4], B1[4];
    FRAG_LD(A0, B0, Wf, yf, 0);
    for (int hp = 0; hp < 8; ++hp) {
      FRAG_LD(A1, B1, Wf, yf, 2*hp+1);
      MFMA16(A0, B0);
      if (hp < 7) FRAG_LD(A0, B0, Wf, yf, 2*hp+2);
      MFMA16(A1, B1);
    }
    {
      int rbase = (lane>>4)*4, colL = lane&15;
      #pragma unroll
      for (int ni = 0; ni < 4; ++ni) {
        int i_local = wn + ni*16 + colL;
        int gn = it*128 + i_local;
        float xn = 1.0f / rnorm[gn];
        int tsel = i_local>>6, ic = i_local&63;
        int kb = ic>>5, g = (ic>>3)&3, j = ic&7;
        int base = tsel*8192 + (kb*512 + g*16)*8 + j;
        #pragma unroll
        for (int mi = 0; mi < 4; ++mi)
          #pragma unroll
          for (int r2 = 0; r2 < 4; ++r2) {
            int o_local = wm + mi*16 + rbase + r2;
            int m = o_local>>4, r = o_local&15;
            sbuf[base + (m*64 + r)*8] = (_Float16)(acc[mi][ni][r2] * xn);
          }
      }
    }
    __syncthreads();
    {
      size_t gbase = ((size_t)((mt*NB + b)*16 + tblk*2))*8192;
      const uint4* src = (const uint4*)sbuf;
      uint4* dst = (uint4*)(htf + gbase);
      #pragma unroll
      for (int k = 0; k < 8; ++k) dst[tid + k*256] = src[tid + k*256];
    }
  }
}

// ---------------- K4: masked softmax w/ inline wave-cooperative exact recheck -> Pf ----------------
__global__ __launch_bounds__(256) void k_softmax(const uint32_t* __restrict__ Mw,
                                                 const uint32_t* __restrict__ Bw,
                                                 const float* __restrict__ x,
                                                 const float* __restrict__ rnorm,
                                                 const float* __restrict__ a_src,
                                                 const float* __restrict__ a_dst,
                                                 _Float16* __restrict__ Pf) {
  __shared__ __align__(16) _Float16 pbuf[4][1032];
  int wid = threadIdx.x>>6, lane = threadIdx.x&63;
  int rowid = blockIdx.x*4 + wid;
  int t = rowid & (NS-1), b = rowid >> 10;
  int n = t + 1;
  const float* as = a_src + b*NS;
  float adv = a_dst[rowid];
  uint32_t w = Mw[(size_t)rowid*32 + (lane>>1)];
  uint32_t bits16 = (lane&1) ? (w>>16) : (w & 0xFFFFu);
  uint32_t w2 = Bw[(size_t)rowid*32 + (lane>>1)];
  uint32_t bb16 = (lane&1) ? (w2>>16) : (w2 & 0xFFFFu);
  int s0 = lane*16;
  // CAUSAL GATE: chunks with s >= n were never written by sim (hold ws poison) -> mask them out
  {
    int rem = n - s0;
    uint32_t gmask = (rem <= 0) ? 0u : (rem >= 16 ? 0xFFFFu : ((1u<<rem)-1u));
    bb16 &= gmask;
  }
  float4 a0 = *(const float4*)&as[s0];
  float4 a1 = *(const float4*)&as[s0+4];
  float4 a2 = *(const float4*)&as[s0+8];
  float4 a3 = *(const float4*)&as[s0+12];
  float va[16] = {a0.x,a0.y,a0.z,a0.w, a1.x,a1.y,a1.z,a1.w,
                  a2.x,a2.y,a2.z,a2.w, a3.x,a3.y,a3.z,a3.w};
  float pr[16];
  #pragma unroll
  for (int k = 0; k < 16; ++k) {
    int s = s0 + k;
    bool on = (s < n) && ((bits16>>k)&1);
    float vv = adv + va[k];
    float v = (vv > 0.f) ? vv : 0.2f*vv;
    pr[k] = on ? v : -INFINITY;
  }
  // ---- inline exact recheck (wave-cooperative); decisions collected in bitmasks (no dyn idx) ----
  uint32_t fix_on = 0u, fix_off = 0u;
  unsigned long long anyb = __ballot(bb16 != 0u);
  if (anyb) {
    float rnt = rnorm[rowid];
    const float* xt = x + (size_t)rowid*ND + lane*8;
    float4 t0v = *(const float4*)xt;
    float4 t1v = *(const float4*)(xt+4);
    while (anyb) {
      int src_lane = __ffsll(anyb) - 1;
      anyb &= anyb - 1ULL;
      unsigned bits = __shfl(bb16, src_lane, 64);
      while (bits) {
        int k = __ffs(bits) - 1;
        bits &= bits - 1u;
        int s = src_lane*16 + k;
        const float* xs = x + ((size_t)(b*NS + s))*ND + lane*8;
        float4 s0v = *(const float4*)xs;
        float4 s1v = *(const float4*)(xs+4);
        float d = 0.f;
        d = fmaf(t0v.x,s0v.x, fmaf(t0v.y,s0v.y, fmaf(t0v.z,s0v.z, fmaf(t0v.w,s0v.w, d))));
        d = fmaf(t1v.x,s1v.x, fmaf(t1v.y,s1v.y, fmaf(t1v.z,s1v.z, fmaf(t1v.w,s1v.w, d))));
        #pragma unroll
        for (int off = 32; off > 0; off >>= 1) d += __shfl_xor(d, off, 64);
        float sim = d * rnt * rnorm[b*NS+s];
        bool on2 = sim > 0.9f;
        if (lane == src_lane) {
          if (on2) fix_on  |= (1u<<k);
          else     fix_off |= (1u<<k);
        }
      }
    }
  }
  #pragma unroll
  for (int k = 0; k < 16; ++k) {
    float vv = adv + va[k];
    float v = (vv > 0.f) ? vv : 0.2f*vv;
    if ((fix_on >>k)&1) pr[k] = v;
    if ((fix_off>>k)&1) pr[k] = -INFINITY;
  }
  // ---- reduction + normalize + frag-order store (r19-proven) ----
  float lm = -INFINITY;
  #pragma unroll
  for (int k = 0; k < 16; ++k) lm = fmaxf(lm, pr[k]);
  #pragma unroll
  for (int off = 32; off > 0; off >>= 1) lm = fmaxf(lm, __shfl_xor(lm, off, 64));
  float ls = 0.f;
  #pragma unroll
  for (int k = 0; k < 16; ++k) { pr[k] = __expf(pr[k] - lm); ls += pr[k]; }
  #pragma unroll
  for (int off = 32; off > 0; off >>= 1) ls += __shfl_xor(ls, off, 64);
  float inv = 1.0f / ls;
  union { _Float16 hh[8]; uint4 u; } pk0, pk1;
  #pragma unroll
  for (int j = 0; j < 8; ++j) pk0.hh[j] = (_Float16)(pr[j]*inv);
  #pragma unroll
  for (int j = 0; j < 8; ++j) pk1.hh[j] = (_Float16)(pr[8+j]*inv);
  *(uint4*)&pbuf[wid][s0]   = pk0.u;
  *(uint4*)&pbuf[wid][s0+8] = pk1.u;
  __syncthreads();
  int t0 = (blockIdx.x*4) & (NS-1);
  int b0 = (blockIdx.x*4) >> 10;
  int end = ((t0 >> 7) + 1) << 7;
  int m = (t0>>4)&7, r0 = t0&15;
  size_t tbase = ((size_t)(b0*8 + (t0>>7)))*131072;
  int nslots = (end>>3)*4;
  for (int u = threadIdx.x; u < nslots; u += 256) {
    int rr = u&3, c8 = u>>2;
    int icol = c8*8;
    int k0c = icol>>6, kb = (icol>>5)&1, g = (icol>>3)&3;
    uint4 v = *(const uint4*)&pbuf[rr][icol];
    *(uint4*)&Pf[tbase + (size_t)k0c*8192 + (size_t)(kb*512 + m*64 + g*16 + r0 + rr)*8] = v;
  }
}

// ---------------- K5: out = relu(P @ h + bias) -- zero-LDS + register prefetch, causal ----------------
__global__ __launch_bounds__(256) void k_pv(const _Float16* __restrict__ Pf,
                                            const _Float16* __restrict__ htf,
                                            const float* __restrict__ bias,
                                            float* __restrict__ out) {
  int bid = blockIdx.x;
  int swz = (bid&7)*64 + (bid>>3);          // bijective: 512 = 8*64
  int b = swz>>5, rem = swz&31, mt = rem>>2, nt = rem&3;
  int tid = threadIdx.x, wid = tid>>6, lane = tid&63;
  int wm = (wid>>1)*64, wn = (wid&1)*64;
  size_t Abase = ((size_t)((b*8 + mt)*16))*8192 + (size_t)lane*8;
  size_t Bbase = ((size_t)((nt*NB + b)*16))*8192 + (size_t)lane*8;
  int aq = (wm>>4), bq = (wn>>4);
  f32x4 acc[4][4] = {};
  int nhp = 2*(mt+1);
  f16x8 A0[4], B0[4], A1[4], B1[4];
  FRAG_LD(A0, B0, Pf, htf, 0);
  for (int hp = 0; hp < nhp; ++hp) {
    FRAG_LD(A1, B1, Pf, htf, 2*hp+1);
    MFMA16(A0, B0);
    if (hp < nhp-1) FRAG_LD(A0, B0, Pf, htf, 2*hp+2);
    MFMA16(A1, B1);
  }
  int m0 = mt*128, n0 = nt*128;
  int rbase = (lane>>4)*4, col = lane&15;
  #pragma unroll
  for (int mi = 0; mi < 4; ++mi)
    #pragma unroll
    for (int ni = 0; ni < 4; ++ni) {
      int gm = m0 + wm + mi*16 + rbase;
      int gn = n0 + wn + ni*16 + col;
      float bv = bias[gn];
      #pragma unroll
      for (int r2 = 0; r2 < 4; ++r2)
        out[((size_t)b*NS + gm + r2)*NO + gn] = fmaxf(acc[mi][ni][r2] + bv, 0.0f);
    }
}

extern "C" void kernel_launch(void* const* d_in, const int* in_sizes, int n_in,
                              void* d_out, int out_size, void* d_ws, size_t ws_size,
                              hipStream_t stream) {
  (void)in_sizes; (void)n_in; (void)out_size; (void)ws_size;
  const float* x       = (const float*)d_in[0];
  const float* W       = (const float*)d_in[1];
  const float* att_src = (const float*)d_in[2];
  const float* att_dst = (const float*)d_in[3];
  const float* bias    = (const float*)d_in[4];
  float* out = (float*)d_out;

  char* ws = (char*)d_ws;
  _Float16*     yf    = (_Float16*)    (ws + 0);           // 16 MB [prep_y..sim_ht]
  _Float16*     htf   = (_Float16*)    (ws + 16777216);    // 16 MB [sim_ht..pv]
  _Float16*     Pf    = (_Float16*)    (ws + 33554432);    // 32 MB [softmax..pv]
  uint16_t*     Mbits = (uint16_t*)    (ws + 67108864);    //  2 MB [sim_ht..softmax]
  uint16_t*     Bbits = (uint16_t*)    (ws + 69206016);    //  2 MB [sim_ht..softmax]
  _Float16*     Wf    = (_Float16*)    (ws + 71303168);    // 512 KB [prep_w2..sim_ht]
  float*        watt_s= (float*)       (ws + 71827456);    //  2 KB
  float*        watt_d= (float*)       (ws + 71829504);    //  2 KB
  float*        rnorm = (float*)       (ws + 71831552);    // 64 KB
  float*        a_src = (float*)       (ws + 71897088);    // 64 KB
  float*        a_dst = (float*)       (ws + 71962624);    // 64 KB

  k_prep_w2<<<dim3(34),   dim3(256), 0, stream>>>(W, att_src, att_dst, Wf, watt_s, watt_d);
  k_prep_y <<<dim3(256),  dim3(256), 0, stream>>>(x, yf, rnorm, a_src, a_dst, watt_s, watt_d);
  k_sim_ht <<<dim3(1088), dim3(256), 0, stream>>>(yf, Wf, rnorm, Mbits, Bbits, htf);
  k_softmax<<<dim3(4096), dim3(256), 0, stream>>>((const uint32_t*)Mbits, (const uint32_t*)Bbits,
                                                  x, rnorm, a_src, a_dst, Pf);
  k_pv     <<<dim3(512),  dim3(256), 0, stream>>>(Pf, htf, bias, out);
}

// Round 22
// 102.974 us; speedup vs baseline: 1.4259x; 1.0414x over previous
//
#include <hip/hip_runtime.h>
#include <hip/hip_bf16.h>
#include <stdint.h>

#define NB 16
#define NS 1024
#define ND 512
#define NO 512
#define NROW (NB*NS)   // 16384
#define SIM_BAND 1.5e-3f

typedef float f32x4 __attribute__((ext_vector_type(4)));
typedef _Float16 f16x8 __attribute__((ext_vector_type(8)));

// ---------------- K1: merged W-prep: blocks 0..31 = Wf frag tiles (f16), 32..33 = watt ----------------
__global__ __launch_bounds__(256) void k_prep_w2(const float* __restrict__ W,
                                                 const float* __restrict__ att_src,
                                                 const float* __restrict__ att_dst,
                                                 _Float16* __restrict__ Wf,
                                                 float* __restrict__ watt_s,
                                                 float* __restrict__ watt_d) {
  __shared__ float as_[512], ad_[512];
  int blk = blockIdx.x, tid = threadIdx.x;
  if (blk < 32) {
    int mt = blk>>3, k0c = blk&7;
    size_t base = ((size_t)(mt*8 + k0c))*8192;
    #pragma unroll
    for (int pp = 0; pp < 4; ++pp) {
      int id = pp*256 + tid;
      int kb = id>>9, m = (id>>6)&7, g = (id>>4)&3, r = id&15;
      int o = mt*128 + m*16 + r;
      int d0 = k0c*64 + kb*32 + g*8;
      union { _Float16 h[8]; uint4 u; } pk;
      #pragma unroll
      for (int j = 0; j < 8; ++j) pk.h[j] = (_Float16)W[(size_t)(d0+j)*NO + o];
      *(uint4*)&Wf[base + id*8] = pk.u;
    }
  } else {
    as_[tid] = att_src[tid]; as_[tid+256] = att_src[tid+256];
    ad_[tid] = att_dst[tid]; ad_[tid+256] = att_dst[tid+256];
    __syncthreads();
    int d = (blk-32)*256 + tid;
    const float* wr = W + (size_t)d*NO;
    float s = 0.f, dd = 0.f;
    for (int o = 0; o < NO; o += 4) {
      float4 w = *(const float4*)&wr[o];
      s  = fmaf(w.x, as_[o], fmaf(w.y, as_[o+1], fmaf(w.z, as_[o+2], fmaf(w.w, as_[o+3], s))));
      dd = fmaf(w.x, ad_[o], fmaf(w.y, ad_[o+1], fmaf(w.z, ad_[o+2], fmaf(w.w, ad_[o+3], dd))));
    }
    watt_s[d] = s;
    watt_d[d] = dd;
  }
}

// ---------------- K2: rnorm + a_src/a_dst (via watt) + yf = f16(x*rn) fragment-order ----------------
__global__ __launch_bounds__(256) void k_prep_y(const float* __restrict__ x,
                                                _Float16* __restrict__ yf,
                                                float* __restrict__ rnorm,
                                                float* __restrict__ a_src,
                                                float* __restrict__ a_dst,
                                                const float* __restrict__ watt_s,
                                                const float* __restrict__ watt_d) {
  __shared__ float ws_[512], wd_[512];
  int tid = threadIdx.x, blk = blockIdx.x;
  ws_[tid] = watt_s[tid]; ws_[tid+256] = watt_s[tid+256];
  wd_[tid] = watt_d[tid]; wd_[tid+256] = watt_d[tid+256];
  __syncthreads();
  int r = tid>>2, q = tid&3;
  int grow = blk*64 + r;
  const float* xr = x + (size_t)grow*ND + q*128;
  float ssq = 0.f, as = 0.f, ad = 0.f;
  #pragma unroll
  for (int c8 = 0; c8 < 16; ++c8) {
    float4 v0 = *(const float4*)&xr[c8*8];
    float4 v1 = *(const float4*)&xr[c8*8+4];
    float vv[8] = {v0.x,v0.y,v0.z,v0.w,v1.x,v1.y,v1.z,v1.w};
    #pragma unroll
    for (int j = 0; j < 8; ++j) {
      int c = q*128 + c8*8 + j;
      ssq = fmaf(vv[j], vv[j], ssq);
      as  = fmaf(vv[j], ws_[c], as);
      ad  = fmaf(vv[j], wd_[c], ad);
    }
  }
  ssq += __shfl_xor(ssq, 1, 64); ssq += __shfl_xor(ssq, 2, 64);
  as  += __shfl_xor(as, 1, 64);  as  += __shfl_xor(as, 2, 64);
  ad  += __shfl_xor(ad, 1, 64);  ad  += __shfl_xor(ad, 2, 64);
  float rn = 1.0f / fmaxf(sqrtf(ssq), 1e-12f);
  if (q == 0) { rnorm[grow] = rn; a_src[grow] = as; a_dst[grow] = ad; }
  int trow = grow & (NS-1), b = grow >> 10;
  int m = (trow>>4)&7, rr = trow&15;
  size_t tilebase = ((size_t)(b*8 + (trow>>7)))*65536;
  #pragma unroll
  for (int c8 = 0; c8 < 16; ++c8) {
    int col = q*128 + c8*8;
    int k0c = col>>6, cc = col&63, kb = cc>>5, g = (cc>>3)&3;
    int id = kb*512 + m*64 + g*16 + rr;
    size_t off = tilebase + (size_t)k0c*8192 + id*8;
    float4 v0 = *(const float4*)&xr[c8*8];
    float4 v1 = *(const float4*)&xr[c8*8+4];
    float vv[8] = {v0.x,v0.y,v0.z,v0.w,v1.x,v1.y,v1.z,v1.w};
    union { _Float16 h[8]; uint4 u; } pk;
    #pragma unroll
    for (int j = 0; j < 8; ++j) pk.h[j] = (_Float16)(vv[j]*rn);   // RTN f16
    *(uint4*)&yf[off] = pk.u;
  }
}

// ---- zero-LDS fragment load (half h covers 32 k-cols): frag = base + h*4096 + q*512 ----
#define FRAG_LD(AH, BH, APTR, BPTR, h) do { \
    _Pragma("unroll") \
    for (int q_ = 0; q_ < 4; ++q_) { \
      AH[q_] = *(const f16x8*)&APTR[Abase + (size_t)(h)*4096 + (size_t)(aq + q_)*512]; \
      BH[q_] = *(const f16x8*)&BPTR[Bbase + (size_t)(h)*4096 + (size_t)(bq + q_)*512]; \
    } \
  } while(0)

#define MFMA16(AH, BH) do { \
    _Pragma("unroll") \
    for (int mi_ = 0; mi_ < 4; ++mi_) \
      _Pragma("unroll") \
      for (int ni_ = 0; ni_ < 4; ++ni_) \
        acc[mi_][ni_] = __builtin_amdgcn_mfma_f32_16x16x32_f16(AH[mi_], BH[ni_], acc[mi_][ni_], 0,0,0); \
  } while(0)

// ---------------- K3 (fused): blocks 0..575 = sim -> Mbits+Bbits; 576..1087 = gemm_ht ----------------
// __launch_bounds__(256, 3): VGPR cap ~168 so BOTH register-prefetch buffer sets stay live.
__global__ __launch_bounds__(256, 3) void k_sim_ht(const _Float16* __restrict__ yf,
                                                   const _Float16* __restrict__ Wf,
                                                   const float* __restrict__ rnorm,
                                                   uint16_t* __restrict__ Mbits,
                                                   uint16_t* __restrict__ Bbits,
                                                   _Float16* __restrict__ htf) {
  __shared__ __align__(16) _Float16 sbuf[16384];   // used only by ht path (output staging)
  int bid0 = blockIdx.x;
  int tid = threadIdx.x, wid = tid>>6, lane = tid&63;
  int wm = (wid>>1)*64, wn = (wid&1)*64;
  int aq = (wm>>4), bq = (wn>>4);
  if (bid0 < 576) {
    // ---- sim path: zero-LDS with register double-buffer prefetch ----
    int swz = (bid0 & 7)*72 + (bid0 >> 3);      // bijective: 576 = 8*72
    int b = swz / 36, p = swz - b*36;
    int ti = 0;
    while ((ti+1)*(ti+2)/2 <= p) ++ti;
    int tj = p - ti*(ti+1)/2;                   // tj <= ti
    size_t Abase = ((size_t)(b*8+ti))*65536 + (size_t)lane*8;
    size_t Bbase = ((size_t)(b*8+tj))*65536 + (size_t)lane*8;
    f32x4 acc[4][4] = {};
    f16x8 A0[4], B0[4], A1[4], B1[4];
    FRAG_LD(A0, B0, yf, yf, 0);
    for (int hp = 0; hp < 8; ++hp) {
      FRAG_LD(A1, B1, yf, yf, 2*hp+1);
      MFMA16(A0, B0);
      if (hp < 7) FRAG_LD(A0, B0, yf, yf, 2*hp+2);
      MFMA16(A1, B1);
    }
    int hi = lane>>4, colL = lane&15;
    #pragma unroll
    for (int mi = 0; mi < 4; ++mi) {
      #pragma unroll
      for (int r2 = 0; r2 < 4; ++r2) {
        int t_g = ti*128 + wm + mi*16 + hi*4 + r2;
        int git = b*NS + t_g;
        #pragma unroll
        for (int ni = 0; ni < 4; ++ni) {
          int s_g = tj*128 + wn + ni*16 + colL;
          float sim = acc[mi][ni][r2];
          bool bit  = (s_g == t_g) || (s_g < t_g && sim > 0.9f);
          bool cond = (s_g < t_g) && (fabsf(sim - 0.9f) <= SIM_BAND);
          unsigned long long bal = __ballot(bit);
          unsigned long long bb  = __ballot(cond);
          if (colL == 0) {
            int widx = (tj*128 + wn + ni*16)>>4;
            Mbits[(size_t)git*64 + widx] = (uint16_t)((bal >> (hi*16)) & 0xFFFFull);
            Bbits[(size_t)git*64 + widx] = (uint16_t)((bb  >> (hi*16)) & 0xFFFFull);
          }
        }
      }
    }
  } else {
    // ---- gemm_ht path: zero-LDS + register prefetch; LDS only for coalesced output ----
    int bidh = bid0 - 576;
    int swz = (bidh&7)*64 + (bidh>>3);          // bijective: 512 = 8*64
    int mt = swz&3, it = swz>>2;
    int b = it>>3, tblk = it&7;
    size_t Abase = ((size_t)mt)*65536 + (size_t)lane*8;
    size_t Bbase = ((size_t)(b*8+tblk))*65536 + (size_t)lane*8;
    f32x4 acc[4][4] = {};
    f16x8 A0[4], B0[4], A1[4], B1[4];
    FRAG_LD(A0, B0, Wf, yf, 0);
    for (int hp = 0; hp < 8; ++hp) {
      FRAG_LD(A1, B1, Wf, yf, 2*hp+1);
      MFMA16(A0, B0);
      if (hp < 7) FRAG_LD(A0, B0, Wf, yf, 2*hp+2);
      MFMA16(A1, B1);
    }
    {
      int rbase = (lane>>4)*4, colL = lane&15;
      #pragma unroll
      for (int ni = 0; ni < 4; ++ni) {
        int i_local = wn + ni*16 + colL;
        int gn = it*128 + i_local;
        float xn = 1.0f / rnorm[gn];
        int tsel = i_local>>6, ic = i_local&63;
        int kb = ic>>5, g = (ic>>3)&3, j = ic&7;
        int base = tsel*8192 + (kb*512 + g*16)*8 + j;
        #pragma unroll
        for (int mi = 0; mi < 4; ++mi)
          #pragma unroll
          for (int r2 = 0; r2 < 4; ++r2) {
            int o_local = wm + mi*16 + rbase + r2;
            int m = o_local>>4, r = o_local&15;
            sbuf[base + (m*64 + r)*8] = (_Float16)(acc[mi][ni][r2] * xn);
          }
      }
    }
    __syncthreads();
    {
      size_t gbase = ((size_t)((mt*NB + b)*16 + tblk*2))*8192;
      const uint4* src = (const uint4*)sbuf;
      uint4* dst = (uint4*)(htf + gbase);
      #pragma unroll
      for (int k = 0; k < 8; ++k) dst[tid + k*256] = src[tid + k*256];
    }
  }
}

// ---------------- K4: masked softmax w/ inline wave-cooperative exact recheck -> Pf ----------------
__global__ __launch_bounds__(256) void k_softmax(const uint32_t* __restrict__ Mw,
                                                 const uint32_t* __restrict__ Bw,
                                                 const float* __restrict__ x,
                                                 const float* __restrict__ rnorm,
                                                 const float* __restrict__ a_src,
                                                 const float* __restrict__ a_dst,
                                                 _Float16* __restrict__ Pf) {
  __shared__ __align__(16) _Float16 pbuf[4][1032];
  int wid = threadIdx.x>>6, lane = threadIdx.x&63;
  int rowid = blockIdx.x*4 + wid;
  int t = rowid & (NS-1), b = rowid >> 10;
  int n = t + 1;
  const float* as = a_src + b*NS;
  float adv = a_dst[rowid];
  uint32_t w = Mw[(size_t)rowid*32 + (lane>>1)];
  uint32_t bits16 = (lane&1) ? (w>>16) : (w & 0xFFFFu);
  uint32_t w2 = Bw[(size_t)rowid*32 + (lane>>1)];
  uint32_t bb16 = (lane&1) ? (w2>>16) : (w2 & 0xFFFFu);
  int s0 = lane*16;
  // CAUSAL GATE: chunks with s >= n were never written by sim (hold ws poison) -> mask them out
  {
    int rem = n - s0;
    uint32_t gmask = (rem <= 0) ? 0u : (rem >= 16 ? 0xFFFFu : ((1u<<rem)-1u));
    bb16 &= gmask;
  }
  float4 a0 = *(const float4*)&as[s0];
  float4 a1 = *(const float4*)&as[s0+4];
  float4 a2 = *(const float4*)&as[s0+8];
  float4 a3 = *(const float4*)&as[s0+12];
  float va[16] = {a0.x,a0.y,a0.z,a0.w, a1.x,a1.y,a1.z,a1.w,
                  a2.x,a2.y,a2.z,a2.w, a3.x,a3.y,a3.z,a3.w};
  float pr[16];
  #pragma unroll
  for (int k = 0; k < 16; ++k) {
    int s = s0 + k;
    bool on = (s < n) && ((bits16>>k)&1);
    float vv = adv + va[k];
    float v = (vv > 0.f) ? vv : 0.2f*vv;
    pr[k] = on ? v : -INFINITY;
  }
  // ---- inline exact recheck (wave-cooperative); decisions collected in bitmasks ----
  uint32_t fix_on = 0u, fix_off = 0u;
  unsigned long long anyb = __ballot(bb16 != 0u);
  if (anyb) {
    float rnt = rnorm[rowid];
    const float* xt = x + (size_t)rowid*ND + lane*8;
    float4 t0v = *(const float4*)xt;
    float4 t1v = *(const float4*)(xt+4);
    while (anyb) {
      int src_lane = __ffsll(anyb) - 1;
      anyb &= anyb - 1ULL;
      unsigned bits = __shfl(bb16, src_lane, 64);
      while (bits) {
        int k = __ffs(bits) - 1;
        bits &= bits - 1u;
        int s = src_lane*16 + k;
        const float* xs = x + ((size_t)(b*NS + s))*ND + lane*8;
        float4 s0v = *(const float4*)xs;
        float4 s1v = *(const float4*)(xs+4);
        float d = 0.f;
        d = fmaf(t0v.x,s0v.x, fmaf(t0v.y,s0v.y, fmaf(t0v.z,s0v.z, fmaf(t0v.w,s0v.w, d))));
        d = fmaf(t1v.x,s1v.x, fmaf(t1v.y,s1v.y, fmaf(t1v.z,s1v.z, fmaf(t1v.w,s1v.w, d))));
        #pragma unroll
        for (int off = 32; off > 0; off >>= 1) d += __shfl_xor(d, off, 64);
        float sim = d * rnt * rnorm[b*NS+s];
        bool on2 = sim > 0.9f;
        if (lane == src_lane) {
          if (on2) fix_on  |= (1u<<k);
          else     fix_off |= (1u<<k);
        }
      }
    }
  }
  #pragma unroll
  for (int k = 0; k < 16; ++k) {
    float vv = adv + va[k];
    float v = (vv > 0.f) ? vv : 0.2f*vv;
    if ((fix_on >>k)&1) pr[k] = v;
    if ((fix_off>>k)&1) pr[k] = -INFINITY;
  }
  // ---- reduction + normalize + frag-order store ----
  float lm = -INFINITY;
  #pragma unroll
  for (int k = 0; k < 16; ++k) lm = fmaxf(lm, pr[k]);
  #pragma unroll
  for (int off = 32; off > 0; off >>= 1) lm = fmaxf(lm, __shfl_xor(lm, off, 64));
  float ls = 0.f;
  #pragma unroll
  for (int k = 0; k < 16; ++k) { pr[k] = __expf(pr[k] - lm); ls += pr[k]; }
  #pragma unroll
  for (int off = 32; off > 0; off >>= 1) ls += __shfl_xor(ls, off, 64);
  float inv = 1.0f / ls;
  union { _Float16 hh[8]; uint4 u; } pk0, pk1;
  #pragma unroll
  for (int j = 0; j < 8; ++j) pk0.hh[j] = (_Float16)(pr[j]*inv);
  #pragma unroll
  for (int j = 0; j < 8; ++j) pk1.hh[j] = (_Float16)(pr[8+j]*inv);
  *(uint4*)&pbuf[wid][s0]   = pk0.u;
  *(uint4*)&pbuf[wid][s0+8] = pk1.u;
  __syncthreads();
  int t0 = (blockIdx.x*4) & (NS-1);
  int b0 = (blockIdx.x*4) >> 10;
  int end = ((t0 >> 7) + 1) << 7;
  int m = (t0>>4)&7, r0 = t0&15;
  size_t tbase = ((size_t)(b0*8 + (t0>>7)))*131072;
  int nslots = (end>>3)*4;
  for (int u = threadIdx.x; u < nslots; u += 256) {
    int rr = u&3, c8 = u>>2;
    int icol = c8*8;
    int k0c = icol>>6, kb = (icol>>5)&1, g = (icol>>3)&3;
    uint4 v = *(const uint4*)&pbuf[rr][icol];
    *(uint4*)&Pf[tbase + (size_t)k0c*8192 + (size_t)(kb*512 + m*64 + g*16 + r0 + rr)*8] = v;
  }
}

// ---------------- K5: out = relu(P @ h + bias) -- zero-LDS + register prefetch, causal ----------------
__global__ __launch_bounds__(256, 3) void k_pv(const _Float16* __restrict__ Pf,
                                               const _Float16* __restrict__ htf,
                                               const float* __restrict__ bias,
                                               float* __restrict__ out) {
  int bid = blockIdx.x;
  int swz = (bid&7)*64 + (bid>>3);          // bijective: 512 = 8*64
  int b = swz>>5, rem = swz&31, mt = rem>>2, nt = rem&3;
  int tid = threadIdx.x, wid = tid>>6, lane = tid&63;
  int wm = (wid>>1)*64, wn = (wid&1)*64;
  size_t Abase = ((size_t)((b*8 + mt)*16))*8192 + (size_t)lane*8;
  size_t Bbase = ((size_t)((nt*NB + b)*16))*8192 + (size_t)lane*8;
  int aq = (wm>>4), bq = (wn>>4);
  f32x4 acc[4][4] = {};
  int nhp = 2*(mt+1);
  f16x8 A0[4], B0[4], A1[4], B1[4];
  FRAG_LD(A0, B0, Pf, htf, 0);
  for (int hp = 0; hp < nhp; ++hp) {
    FRAG_LD(A1, B1, Pf, htf, 2*hp+1);
    MFMA16(A0, B0);
    if (hp < nhp-1) FRAG_LD(A0, B0, Pf, htf, 2*hp+2);
    MFMA16(A1, B1);
  }
  int m0 = mt*128, n0 = nt*128;
  int rbase = (lane>>4)*4, col = lane&15;
  #pragma unroll
  for (int mi = 0; mi < 4; ++mi)
    #pragma unroll
    for (int ni = 0; ni < 4; ++ni) {
      int gm = m0 + wm + mi*16 + rbase;
      int gn = n0 + wn + ni*16 + col;
      float bv = bias[gn];
      #pragma unroll
      for (int r2 = 0; r2 < 4; ++r2)
        out[((size_t)b*NS + gm + r2)*NO + gn] = fmaxf(acc[mi][ni][r2] + bv, 0.0f);
    }
}

extern "C" void kernel_launch(void* const* d_in, const int* in_sizes, int n_in,
                              void* d_out, int out_size, void* d_ws, size_t ws_size,
                              hipStream_t stream) {
  (void)in_sizes; (void)n_in; (void)out_size; (void)ws_size;
  const float* x       = (const float*)d_in[0];
  const float* W       = (const float*)d_in[1];
  const float* att_src = (const float*)d_in[2];
  const float* att_dst = (const float*)d_in[3];
  const float* bias    = (const float*)d_in[4];
  float* out = (float*)d_out;

  char* ws = (char*)d_ws;
  _Float16*     yf    = (_Float16*)    (ws + 0);           // 16 MB [prep_y..sim_ht]
  _Float16*     htf   = (_Float16*)    (ws + 16777216);    // 16 MB [sim_ht..pv]
  _Float16*     Pf    = (_Float16*)    (ws + 33554432);    // 32 MB [softmax..pv]
  uint16_t*     Mbits = (uint16_t*)    (ws + 67108864);    //  2 MB [sim_ht..softmax]
  uint16_t*     Bbits = (uint16_t*)    (ws + 69206016);    //  2 MB [sim_ht..softmax]
  _Float16*     Wf    = (_Float16*)    (ws + 71303168);    // 512 KB [prep_w2..sim_ht]
  float*        watt_s= (float*)       (ws + 71827456);    //  2 KB
  float*        watt_d= (float*)       (ws + 71829504);    //  2 KB
  float*        rnorm = (float*)       (ws + 71831552);    // 64 KB
  float*        a_src = (float*)       (ws + 71897088);    // 64 KB
  float*        a_dst = (float*)       (ws + 71962624);    // 64 KB

  k_prep_w2<<<dim3(34),   dim3(256), 0, stream>>>(W, att_src, att_dst, Wf, watt_s, watt_d);
  k_prep_y <<<dim3(256),  dim3(256), 0, stream>>>(x, yf, rnorm, a_src, a_dst, watt_s, watt_d);
  k_sim_ht <<<dim3(1088), dim3(256), 0, stream>>>(yf, Wf, rnorm, Mbits, Bbits, htf);
  k_softmax<<<dim3(4096), dim3(256), 0, stream>>>((const uint32_t*)Mbits, (const uint32_t*)Bbits,
                                                  x, rnorm, a_src, a_dst, Pf);
  k_pv     <<<dim3(512),  dim3(256), 0, stream>>>(Pf, htf, bias, out);
}